// Round 15
// baseline (561.740 us; speedup 1.0000x reference)
//
#include <hip/hip_runtime.h>
#include <hip/hip_bf16.h>
#include <math.h>

#define NN 2048          // n_nodes
#define NH 8             // heads
#define LRALPHA 0.2f
#define EMAX (1 << 17)   // edge-capacity stride for weight buffers (nnz ~ 87k)

typedef short bf16x8 __attribute__((ext_vector_type(8)));
typedef float f32x4  __attribute__((ext_vector_type(4)));

static __device__ __forceinline__ float lrelu(float x){ return x > 0.f ? x : LRALPHA * x; }
static __device__ __forceinline__ float elu(float x){ return x > 0.f ? x : expm1f(x); }

static __device__ __forceinline__ unsigned short f2bf(float v){
    unsigned u = __float_as_uint(v);
    unsigned r = (u + 0x7fffu + ((u >> 16) & 1u)) >> 16;
    return (unsigned short)r;
}
static __device__ __forceinline__ float bf2f(unsigned short b){
    return __uint_as_float(((unsigned)b) << 16);
}
static __device__ __forceinline__ float blo(unsigned u){ return __uint_as_float(u << 16); }
static __device__ __forceinline__ float bhi(unsigned u){ return __uint_as_float(u & 0xffff0000u); }

static __device__ __forceinline__ void gload16(const void* g, void* l){
    __builtin_amdgcn_global_load_lds((const __attribute__((address_space(1))) void*)g,
                                     (__attribute__((address_space(3))) void*)l, 16, 0, 0);
}

// ---------------- CSR build (deterministic, sorted by column) ----------------
__global__ void k_count(const float* __restrict__ adj, int* __restrict__ deg) {
    int gw   = (blockIdx.x * blockDim.x + threadIdx.x) >> 6;
    int lane = threadIdx.x & 63;
    if (gw >= NN) return;
    const float* row = adj + (size_t)gw * NN;
    int cnt = 0;
    for (int j = lane; j < NN; j += 64) cnt += (row[j] > 0.f) ? 1 : 0;
    #pragma unroll
    for (int off = 32; off; off >>= 1) cnt += __shfl_down(cnt, off);
    if (lane == 0) deg[gw] = cnt;
}

__global__ void k_scan(const int* __restrict__ deg, int* __restrict__ rp) {
    __shared__ int a[NN], b[NN];
    int t = threadIdx.x;                       // 1024 threads
    for (int i = t; i < NN; i += 1024) a[i] = deg[i];
    __syncthreads();
    int* src = a; int* dst = b;
    for (int off = 1; off < NN; off <<= 1) {
        for (int i = t; i < NN; i += 1024)
            dst[i] = src[i] + (i >= off ? src[i - off] : 0);
        __syncthreads();
        int* tmp = src; src = dst; dst = tmp;
    }
    for (int i = t; i < NN; i += 1024) rp[i + 1] = src[i];
    if (t == 0) rp[0] = 0;
}

__global__ void k_fill(const float* __restrict__ adj, const int* __restrict__ rp,
                       int* __restrict__ ci) {
    int gw   = (blockIdx.x * blockDim.x + threadIdx.x) >> 6;
    int lane = threadIdx.x & 63;
    if (gw >= NN) return;
    const float* row = adj + (size_t)gw * NN;
    int base = rp[gw];
    for (int j0 = 0; j0 < NN; j0 += 64) {
        bool v = row[j0 + lane] > 0.f;
        unsigned long long m = __ballot(v);
        int pos = __popcll(m & ((1ULL << lane) - 1ULL));
        if (v) ci[base + pos] = j0 + lane;
        base += __popcll(m);
    }
}

// ---------------- split fp32 -> bf16 hi/lo (input x only) ----------------
__global__ void k_split(const float* __restrict__ src, unsigned short* __restrict__ hi,
                        unsigned short* __restrict__ lo, int n4) {
    int i = blockIdx.x * 256 + threadIdx.x;
    if (i >= n4) return;
    float4 v = ((const float4*)src)[i];
    ushort4 h, l;
    h.x = f2bf(v.x); l.x = f2bf(v.x - bf2f(h.x));
    h.y = f2bf(v.y); l.y = f2bf(v.y - bf2f(h.y));
    h.z = f2bf(v.z); l.z = f2bf(v.z - bf2f(h.z));
    h.w = f2bf(v.w); l.w = f2bf(v.w - bf2f(h.w));
    ((ushort4*)hi)[i] = h;
    ((ushort4*)lo)[i] = l;
}

// ------- ALL weight transposes+splits in ONE launch ----
struct TSDesc {
    const float* B[12];
    unsigned short* bh[12];
    unsigned short* bl[12];
    int K[12], Nc[12], hs[12];
    int start[13];
};

__global__ __launch_bounds__(256) void k_tsplit_all(TSDesc d) {
    __shared__ float t[64][65];
    int b = blockIdx.x;
    int s = 0;
    while (b >= d.start[s + 1]) s++;
    int lb = b - d.start[s];
    int K = d.K[s], Nc = d.Nc[s], hs = d.hs[s];
    int tilesX = K >> 6;
    int kb = (lb % tilesX) * 64, cb = (lb / tilesX) * 64;
    const float* B = d.B[s];
    unsigned short* bth = d.bh[s];
    unsigned short* btl = d.bl[s];

    int tid = threadIdx.x;
    #pragma unroll
    for (int i = 0; i < 16; i++) {
        int idx = i * 256 + tid;
        int kk = idx >> 6, cc = idx & 63;
        int c = cb + cc, k = kb + kk;
        float v;
        if (hs < 0) v = B[(size_t)k * Nc + c];
        else {
            int hid = 1 << hs; int head = c >> hs; int dd = c & (hid - 1);
            v = B[((size_t)head * K + k) * hid + dd];
        }
        t[kk][cc] = v;
    }
    __syncthreads();
    #pragma unroll
    for (int i = 0; i < 16; i++) {
        int idx = i * 256 + tid;
        int cc = idx >> 6, kk = idx & 63;
        float v = t[kk][cc];
        unsigned short h = f2bf(v);
        size_t o = (size_t)(cb + cc) * K + kb + kk;
        bth[o] = h;
        btl[o] = f2bf(v - bf2f(h));
    }
}

// ---------- split-bf16 MFMA GEMM, 256 threads, 128(M) x 64(N) tile ----------
// (unchanged from round 12/14 best-known config)
template<int OUT, int NT>
__global__ __launch_bounds__(256) void k_mfma(
    const unsigned short* __restrict__ Ah, const unsigned short* __restrict__ Al,
    const unsigned short* __restrict__ Bh, const unsigned short* __restrict__ Bl,
    float* __restrict__ Cf, unsigned short* __restrict__ Cb, int Nc, int K, int Kc,
    const float* __restrict__ avec, float* __restrict__ sg1, float* __restrict__ sg2,
    int hs, int aoff, int nx, int nz, int zcol)
{
    constexpr int ALB = 4096;                       // ushort units (NT=3 only)
    constexpr int BHB = (NT == 3) ? 8192 : 4096;
    constexpr int BLB = BHB + 2048;
    __shared__ unsigned short lds[(NT == 3) ? 12288 : 8192];  // 24KB / 16KB
    int tid = threadIdx.x, lane = tid & 63, w = tid >> 6;

    int g = blockIdx.x;
    int xcd = g & 7, q = g >> 3;
    int x, y, z;
    if (zcol) {
        int zper = nz >> 3;
        z = xcd + 8 * (q % zper);
        int r = q / zper;
        int nxy = nx * 16;
        int r2 = r + xcd * (nxy >> 3); if (r2 >= nxy) r2 -= nxy;
        x = r2 % nx; y = r2 / nx;
    } else {
        y = xcd + 8 * (q & 1);
        x = q >> 1; z = 0;
    }
    int m0 = y * 128, n0 = x * 64;
    int kbeg = z * Kc;

    int ra0 = tid >> 2;       int ga0 = ((tid & 3) - (ra0 >> 1)) & 3;
    int ra1 = 64 + (tid >> 2); int ga1 = ((tid & 3) - (ra1 >> 1)) & 3;
    int rb  = tid >> 2;       int gb  = ((tid & 3) - (rb >> 1)) & 3;
    const unsigned short* pAh0 = Ah + (size_t)(m0 + ra0) * K + kbeg + ga0 * 8;
    const unsigned short* pAh1 = Ah + (size_t)(m0 + ra1) * K + kbeg + ga1 * 8;
    const unsigned short* pAl0 = (NT == 3) ? Al + (size_t)(m0 + ra0) * K + kbeg + ga0 * 8 : nullptr;
    const unsigned short* pAl1 = (NT == 3) ? Al + (size_t)(m0 + ra1) * K + kbeg + ga1 * 8 : nullptr;
    const unsigned short* pBh  = Bh + (size_t)(n0 + rb) * K + kbeg + gb * 8;
    const unsigned short* pBl  = Bl + (size_t)(n0 + rb) * K + kbeg + gb * 8;
    unsigned short* dA0 = &lds[w * 512];
    unsigned short* dA1 = &lds[2048 + w * 512];
    unsigned short* dB  = &lds[BHB + w * 512];

    int wr = w >> 1, wc = w & 1;
    int offA[4], offB[2];
    #pragma unroll
    for (int m = 0; m < 4; m++) {
        int row = wr * 64 + m * 16 + (lane & 15); int gg = lane >> 4;
        offA[m] = (row * 4 + ((gg + (row >> 1)) & 3)) * 8;
    }
    #pragma unroll
    for (int n = 0; n < 2; n++) {
        int row = wc * 32 + n * 16 + (lane & 15); int gg = lane >> 4;
        offB[n] = (row * 4 + ((gg + (row >> 1)) & 3)) * 8;
    }

    f32x4 acc[4][2];
    #pragma unroll
    for (int m = 0; m < 4; m++)
        #pragma unroll
        for (int n = 0; n < 2; n++) acc[m][n] = (f32x4){0.f, 0.f, 0.f, 0.f};

    int nk = Kc >> 5;
    for (int ks = 0; ks < nk; ks++) {
        gload16(pAh0, dA0);
        gload16(pAh1, dA1);
        if (NT == 3) { gload16(pAl0, dA0 + ALB); gload16(pAl1, dA1 + ALB); }
        gload16(pBh, dB);
        gload16(pBl, dB + 2048);
        pAh0 += 32; pAh1 += 32;
        if (NT == 3) { pAl0 += 32; pAl1 += 32; }
        pBh += 32; pBl += 32;
        __syncthreads();
        bf16x8 ah[4], al[4], bh[2], bl[2];
        #pragma unroll
        for (int m = 0; m < 4; m++) {
            ah[m] = *(const bf16x8*)&lds[offA[m]];
            if (NT == 3) al[m] = *(const bf16x8*)&lds[ALB + offA[m]];
        }
        #pragma unroll
        for (int n = 0; n < 2; n++) {
            bh[n] = *(const bf16x8*)&lds[BHB + offB[n]];
            bl[n] = *(const bf16x8*)&lds[BLB + offB[n]];
        }
        #pragma unroll
        for (int m = 0; m < 4; m++)
            #pragma unroll
            for (int n = 0; n < 2; n++) {
                acc[m][n] = __builtin_amdgcn_mfma_f32_16x16x32_bf16(ah[m], bh[n], acc[m][n], 0, 0, 0);
                if (NT == 3)
                    acc[m][n] = __builtin_amdgcn_mfma_f32_16x16x32_bf16(al[m], bh[n], acc[m][n], 0, 0, 0);
                acc[m][n] = __builtin_amdgcn_mfma_f32_16x16x32_bf16(ah[m], bl[n], acc[m][n], 0, 0, 0);
            }
        __syncthreads();
    }

    size_t pbase = (size_t)z * NN * Nc;
    #pragma unroll
    for (int m = 0; m < 4; m++)
        #pragma unroll
        for (int n = 0; n < 2; n++) {
            int row = m0 + wr * 64 + m * 16 + (lane >> 4) * 4;
            int col = n0 + wc * 32 + n * 16 + (lane & 15);
            #pragma unroll
            for (int r = 0; r < 4; r++) {
                float v = acc[m][n][r];
                if (OUT == 0) Cb[(size_t)(row + r) * Nc + col] = f2bf(v);
                else          Cf[pbase + (size_t)(row + r) * Nc + col] = v;
            }
        }

    if (OUT == 0) {
        int head = (hs >= 0) ? (n0 >> hs) : 0;
        const float* ab = avec + head * 2 * aoff;
        float av1[2], av2[2];
        int colbase = n0 + wc * 32 + (lane & 15);
        #pragma unroll
        for (int n = 0; n < 2; n++) {
            int c = colbase + n * 16;
            int dd = (hs >= 0) ? (c & (aoff - 1)) : c;
            av1[n] = ab[dd];
            av2[n] = ab[dd + aoff];
        }
        #pragma unroll
        for (int m = 0; m < 4; m++)
            #pragma unroll
            for (int r = 0; r < 4; r++) {
                float p1 = 0.f, p2 = 0.f;
                #pragma unroll
                for (int n = 0; n < 2; n++) {
                    float v = acc[m][n][r];
                    p1 += v * av1[n];
                    p2 += v * av2[n];
                }
                #pragma unroll
                for (int o = 1; o < 16; o <<= 1) {
                    p1 += __shfl_xor(p1, o);
                    p2 += __shfl_xor(p2, o);
                }
                if ((lane & 15) == 0) {
                    int row = m0 + wr * 64 + m * 16 + (lane >> 4) * 4 + r;
                    atomicAdd(&sg1[head * NN + row], p1);
                    atomicAdd(&sg2[head * NN + row], p2);
                }
            }
    }
}

// ------- split-K reducer: 4 waves/block, one row per wave -------
__global__ __launch_bounds__(256) void k_red(
    const float* __restrict__ part, float* __restrict__ ho,
    const float* __restrict__ ao, float* __restrict__ t1, float* __restrict__ t2,
    int fout, int sko)
{
    int wid = threadIdx.x >> 6;
    int lane = threadIdx.x & 63;
    int row = blockIdx.x * 4 + wid;
    int C4 = fout >> 2;
    const float4* p4 = (const float4*)part;
    size_t stride4 = (size_t)NN * C4;
    float d1 = 0.f, d2 = 0.f;
    for (int c = lane; c < C4; c += 64) {
        size_t o = (size_t)row * C4 + c;
        float4 s = p4[o];
        for (int zz = 1; zz < sko; zz++) {
            float4 v = p4[o + (size_t)zz * stride4];
            s.x += v.x; s.y += v.y; s.z += v.z; s.w += v.w;
        }
        ((float4*)ho)[o] = s;
        int cc = c * 4;
        d1 += s.x * ao[cc]        + s.y * ao[cc + 1]
            + s.z * ao[cc + 2]    + s.w * ao[cc + 3];
        d2 += s.x * ao[fout + cc]     + s.y * ao[fout + cc + 1]
            + s.z * ao[fout + cc + 2] + s.w * ao[fout + cc + 3];
    }
    #pragma unroll
    for (int o = 32; o; o >>= 1) { d1 += __shfl_xor(d1, o); d2 += __shfl_xor(d2, o); }
    if (lane == 0) { t1[row] = d1; t2[row] = d2; }
}

// ------- per-edge softmax weights, ALL heads: one wave per node, 2-sweep online -------
__global__ __launch_bounds__(256) void k_w(
    const float* __restrict__ s1, const float* __restrict__ s2,
    const int* __restrict__ rp, const int* __restrict__ ci,
    float* __restrict__ wt)
{
    int wid = threadIdx.x >> 6, lane = threadIdx.x & 63;
    int i = blockIdx.x * 4 + wid;
    int base = rp[i], deg = rp[i + 1] - base;
    #pragma unroll 1
    for (int h = 0; h < NH; h++) {
        float s1i = s1[h * NN + i];
        const float* s2h = s2 + h * NN;
        float m = -1e30f, s = 0.f;
        for (int k0 = 0; k0 < deg; k0 += 64) {
            int n = min(64, deg - k0);
            float e = -1e30f;
            if (lane < n) e = lrelu(s1i + s2h[ci[base + k0 + lane]]);
            float bm = e;
            #pragma unroll
            for (int o = 32; o; o >>= 1) bm = fmaxf(bm, __shfl_xor(bm, o));
            float m2 = fmaxf(m, bm);
            float wv = (lane < n) ? expf(e - m2) : 0.f;
            float bs = wv;
            #pragma unroll
            for (int o = 32; o; o >>= 1) bs += __shfl_xor(bs, o);
            s = s * expf(m - m2) + bs;
            m = m2;
        }
        float inv = 1.f / s;
        for (int k0 = 0; k0 < deg; k0 += 64) {
            int n = min(64, deg - k0);
            if (lane < n) {
                float e = lrelu(s1i + s2h[ci[base + k0 + lane]]);
                wt[(size_t)h * EMAX + base + k0 + lane] = expf(e - m) * inv;
            }
        }
    }
}

// ------- per-edge softmax weights, single output head -------
__global__ __launch_bounds__(256) void k_wo(
    const float* __restrict__ t1, const float* __restrict__ t2,
    const int* __restrict__ rp, const int* __restrict__ ci,
    float* __restrict__ wto)
{
    int wid = threadIdx.x >> 6, lane = threadIdx.x & 63;
    int i = blockIdx.x * 4 + wid;
    int base = rp[i], deg = rp[i + 1] - base;
    float s1i = t1[i];
    float m = -1e30f, s = 0.f;
    for (int k0 = 0; k0 < deg; k0 += 64) {
        int n = min(64, deg - k0);
        float e = -1e30f;
        if (lane < n) e = lrelu(s1i + t2[ci[base + k0 + lane]]);
        float bm = e;
        #pragma unroll
        for (int o = 32; o; o >>= 1) bm = fmaxf(bm, __shfl_xor(bm, o));
        float m2 = fmaxf(m, bm);
        float wv = (lane < n) ? expf(e - m2) : 0.f;
        float bs = wv;
        #pragma unroll
        for (int o = 32; o; o >>= 1) bs += __shfl_xor(bs, o);
        s = s * expf(m - m2) + bs;
        m = m2;
    }
    float inv = 1.f / s;
    for (int k0 = 0; k0 < deg; k0 += 64) {
        int n = min(64, deg - k0);
        if (lane < n) {
            float e = lrelu(s1i + t2[ci[base + k0 + lane]]);
            wto[base + k0 + lane] = expf(e - m) * inv;
        }
    }
}

// ------------- BIG gather: 4 waves/block, one (node,head) per wave, pure gather -------------
__global__ __launch_bounds__(256) void k_gab(
    const unsigned short* __restrict__ hh, const float* __restrict__ wt,
    const int* __restrict__ rp, const int* __restrict__ ci,
    unsigned short* __restrict__ outH, int hid, int HD, int c8sh)
{
    __shared__ float    wls[256];
    __shared__ unsigned cls[256];

    int tid = threadIdx.x;
    int wid = tid >> 6;
    int lane = tid & 63;
    int head = blockIdx.x & (NH - 1);
    int i    = (blockIdx.x >> 3) * 4 + wid;
    float* wlsw = wls + wid * 64;
    unsigned* clsw = cls + wid * 64;

    int base = rp[i], deg = rp[i + 1] - base;
    const float* wth = wt + (size_t)head * EMAX + base;

    int C8  = 1 << c8sh;                  // ushort8 cols per head slice (16/32/64)
    int G   = 64 >> c8sh;                 // neighbor groups (4/2/1)
    int col = lane & (C8 - 1);
    int grp = lane >> c8sh;

    const uint4* h4 = (const uint4*)hh;
    unsigned hoff8 = (unsigned)(head * hid) >> 3;
    unsigned ld8   = (unsigned)HD >> 3;

    float a0=0,a1=0,a2=0,a3=0,a4=0,a5=0,a6=0,a7=0;

    for (int k0 = 0; k0 < deg; k0 += 64) {
        int n = min(64, deg - k0);
        if (lane < n) {
            wlsw[lane] = wth[k0 + lane];
            clsw[lane] = (unsigned)ci[base + k0 + lane] * ld8 + hoff8;
        }
        // wave-synchronous LDS (single wave writes+reads; no barrier needed)
        float q0=0,q1=0,q2=0,q3=0,q4=0,q5=0,q6=0,q7=0;
        int k = grp;
        for (; k + G < n; k += 2 * G) {
            float w0 = wlsw[k], w1 = wlsw[k + G];
            uint4 u0 = h4[clsw[k]     + col];
            uint4 u1 = h4[clsw[k + G] + col];
            a0 += w0 * blo(u0.x); a1 += w0 * bhi(u0.x);
            a2 += w0 * blo(u0.y); a3 += w0 * bhi(u0.y);
            a4 += w0 * blo(u0.z); a5 += w0 * bhi(u0.z);
            a6 += w0 * blo(u0.w); a7 += w0 * bhi(u0.w);
            q0 += w1 * blo(u1.x); q1 += w1 * bhi(u1.x);
            q2 += w1 * blo(u1.y); q3 += w1 * bhi(u1.y);
            q4 += w1 * blo(u1.z); q5 += w1 * bhi(u1.z);
            q6 += w1 * blo(u1.w); q7 += w1 * bhi(u1.w);
        }
        if (k < n) {
            float w0 = wlsw[k];
            uint4 u0 = h4[clsw[k] + col];
            a0 += w0 * blo(u0.x); a1 += w0 * bhi(u0.x);
            a2 += w0 * blo(u0.y); a3 += w0 * bhi(u0.y);
            a4 += w0 * blo(u0.z); a5 += w0 * bhi(u0.z);
            a6 += w0 * blo(u0.w); a7 += w0 * bhi(u0.w);
        }
        a0+=q0; a1+=q1; a2+=q2; a3+=q3; a4+=q4; a5+=q5; a6+=q6; a7+=q7;
    }

    // cross-group reduction via register shuffles (G=1: none)
    #pragma unroll
    for (int o = 64; o > 1; o >>= 1) {
        if (o > C8) {
            int m = o >> 1;
            a0 += __shfl_xor(a0, m); a1 += __shfl_xor(a1, m);
            a2 += __shfl_xor(a2, m); a3 += __shfl_xor(a3, m);
            a4 += __shfl_xor(a4, m); a5 += __shfl_xor(a5, m);
            a6 += __shfl_xor(a6, m); a7 += __shfl_xor(a7, m);
        }
    }

    if (grp == 0) {
        float v[8] = {a0,a1,a2,a3,a4,a5,a6,a7};   // weights pre-normalized
        #pragma unroll
        for (int e2 = 0; e2 < 8; e2++) v[e2] = elu(v[e2]);
        unsigned short hh_[8];
        #pragma unroll
        for (int e2 = 0; e2 < 8; e2++) hh_[e2] = f2bf(v[e2]);
        size_t ob = ((size_t)i * HD + head * hid) >> 3;
        uint4 ph;
        ph.x = (unsigned)hh_[0] | ((unsigned)hh_[1] << 16);
        ph.y = (unsigned)hh_[2] | ((unsigned)hh_[3] << 16);
        ph.z = (unsigned)hh_[4] | ((unsigned)hh_[5] << 16);
        ph.w = (unsigned)hh_[6] | ((unsigned)hh_[7] << 16);
        ((uint4*)outH)[ob + col] = ph;
    }
}

// ------------- SMALL gather: 4 waves/block, one (node,slice) per wave -------------
__global__ __launch_bounds__(256) void k_gas(
    const float* __restrict__ hsrc, const float* __restrict__ wto,
    const int* __restrict__ rp, const int* __restrict__ ci,
    float* __restrict__ outF, unsigned short* __restrict__ outH,
    int fout, int SCtot)
{
    __shared__ float    wls[256];
    __shared__ unsigned cls[256];

    int tid = threadIdx.x;
    int wid = tid >> 6;
    int lane = tid & 63;
    int task = blockIdx.x * 4 + wid;
    int i   = task / SCtot;
    int sc  = task - i * SCtot;
    float* wlsw = wls + wid * 64;
    unsigned* clsw = cls + wid * 64;

    int base = rp[i], deg = rp[i + 1] - base;

    int C4tot = fout >> 2;
    int soff  = sc * 64;
    int C4s   = min(64, C4tot - soff);        // 64 or 32 (pow2)
    int c4sh  = 31 - __clz(C4s);
    int col = lane & (C4s - 1);
    int grp = lane >> c4sh;
    int G   = 64 >> c4sh;

    const float4* h4 = (const float4*)hsrc;
    unsigned ld4 = (unsigned)fout >> 2;

    float4 acc = make_float4(0.f, 0.f, 0.f, 0.f);

    for (int k0 = 0; k0 < deg; k0 += 64) {
        int n = min(64, deg - k0);
        if (lane < n) {
            wlsw[lane] = wto[base + k0 + lane];
            clsw[lane] = (unsigned)ci[base + k0 + lane] * ld4 + soff;
        }
        float4 q = make_float4(0,0,0,0);
        int k = grp;
        for (; k + G < n; k += 2 * G) {
            float w0 = wlsw[k], w1 = wlsw[k + G];
            float4 h0 = h4[clsw[k]     + col];
            float4 h1 = h4[clsw[k + G] + col];
            acc.x += w0 * h0.x; acc.y += w0 * h0.y; acc.z += w0 * h0.z; acc.w += w0 * h0.w;
            q.x   += w1 * h1.x; q.y   += w1 * h1.y; q.z   += w1 * h1.z; q.w   += w1 * h1.w;
        }
        if (k < n) {
            float w0 = wlsw[k];
            float4 h0 = h4[clsw[k] + col];
            acc.x += w0 * h0.x; acc.y += w0 * h0.y; acc.z += w0 * h0.z; acc.w += w0 * h0.w;
        }
        acc.x += q.x; acc.y += q.y; acc.z += q.z; acc.w += q.w;
    }

    #pragma unroll
    for (int o = 64; o > 1; o >>= 1) {
        if (o > C4s) {
            int m = o >> 1;
            acc.x += __shfl_xor(acc.x, m); acc.y += __shfl_xor(acc.y, m);
            acc.z += __shfl_xor(acc.z, m); acc.w += __shfl_xor(acc.w, m);
        }
    }

    if (grp == 0) {
        float4 val;
        val.x = elu(acc.x); val.y = elu(acc.y);
        val.z = elu(acc.z); val.w = elu(acc.w);
        size_t o4 = (size_t)i * ld4 + soff + col;
        if (outF) ((float4*)outF)[o4] = val;
        ushort4 h;
        h.x = f2bf(val.x); h.y = f2bf(val.y);
        h.z = f2bf(val.z); h.w = f2bf(val.w);
        ((ushort4*)outH)[o4] = h;
    }
}

// ---------------- host driver ----------------
extern "C" void kernel_launch(void* const* d_in, const int* in_sizes, int n_in,
                              void* d_out, int out_size, void* d_ws, size_t ws_size,
                              hipStream_t stream)
{
    const float* x   = (const float*)d_in[0];
    const float* adj = (const float*)d_in[1];
    struct L { int fin, hid, fout; };
    const L dims[6] = {{256,128,128},{128,256,256},{256,512,384},
                       {384,512,256},{256,256,128},{128,128,256}};
    const int SKwo[6] = {16, 8, 8, 8, 16, 8};
    const int SB = 2 * NH * NN;              // per-layer s1/s2 floats

    char* ws = (char*)d_ws;
    size_t off = 0;
    auto alloc = [&](size_t bytes) -> void* {
        void* p = ws + off;
        off = (off + bytes + 255) & ~(size_t)255;
        return p;
    };
    int*   rp   = (int*)alloc((NN + 1) * sizeof(int));
    int*   deg  = (int*)alloc(NN * sizeof(int));
    int*   ci   = (int*)alloc((size_t)(1 << 20) * sizeof(int));
    unsigned short* hh  = (unsigned short*)alloc((size_t)NN * 4096 * 2);  // bf16 h
    unsigned short* ghi = (unsigned short*)alloc((size_t)NN * 4096 * 2);  // bf16 hcat
    unsigned short* xhi = (unsigned short*)alloc((size_t)NN * 512 * 2);
    unsigned short* xlo = (unsigned short*)alloc((size_t)NN * 512 * 2);
    float* sball  = (float*)alloc((size_t)6 * SB * sizeof(float));        // all-layer s1/s2
    float* hopart = (float*)alloc((size_t)NN * 3072 * sizeof(float));     // split-K partials
    float* ho     = (float*)alloc((size_t)NN * 384 * sizeof(float));      // reduced ho (fp32)
    float* t12    = (float*)alloc((size_t)2 * NN * sizeof(float));        // t1/t2
    float* wt     = (float*)alloc((size_t)NH * EMAX * sizeof(float));     // per-head edge weights
    float* wto    = (float*)alloc((size_t)EMAX * sizeof(float));          // output-head edge weights

    unsigned short* whh[6]; unsigned short* whl[6];
    unsigned short* woh[6]; unsigned short* wol[6];
    TSDesc td;
    int nblk = 0;
    for (int l = 0; l < 6; l++) {
        int fin = dims[l].fin, hid = dims[l].hid, fout = dims[l].fout;
        int HD = NH * hid;
        size_t szWh = (size_t)fin * HD, szWo = (size_t)HD * fout;
        whh[l] = (unsigned short*)alloc(szWh * 2);
        whl[l] = (unsigned short*)alloc(szWh * 2);
        woh[l] = (unsigned short*)alloc(szWo * 2);
        wol[l] = (unsigned short*)alloc(szWo * 2);
        int hs = (hid == 128) ? 7 : (hid == 256) ? 8 : 9;
        td.B[2*l] = (const float*)d_in[2 + l * 4 + 0];
        td.bh[2*l] = whh[l]; td.bl[2*l] = whl[l];
        td.K[2*l] = fin; td.Nc[2*l] = HD; td.hs[2*l] = hs;
        td.start[2*l] = nblk; nblk += (fin / 64) * (HD / 64);
        td.B[2*l+1] = (const float*)d_in[2 + l * 4 + 2];
        td.bh[2*l+1] = woh[l]; td.bl[2*l+1] = wol[l];
        td.K[2*l+1] = HD; td.Nc[2*l+1] = fout; td.hs[2*l+1] = -1;
        td.start[2*l+1] = nblk; nblk += (HD / 64) * (fout / 64);
    }
    td.start[12] = nblk;

    // ---- front matter: one memset (s1/s2 only) + CSR + x split + weight splits ----
    hipMemsetAsync(sball, 0, (size_t)6 * SB * sizeof(float), stream);
    k_count<<<NN / 4, 256, 0, stream>>>(adj, deg);
    k_scan <<<1, 1024, 0, stream>>>(deg, rp);
    k_fill <<<NN / 4, 256, 0, stream>>>(adj, rp, ci);
    k_split<<<(NN * 256 / 4 + 255) / 256, 256, 0, stream>>>(x, xhi, xlo, NN * 256 / 4);
    k_tsplit_all<<<nblk, 256, 0, stream>>>(td);

    for (int l = 0; l < 6; l++) {
        int fin = dims[l].fin, hid = dims[l].hid, fout = dims[l].fout;
        int HD = NH * hid;
        int hs = (hid == 128) ? 7 : (hid == 256) ? 8 : 9;
        int c8sh = hs - 3;                     // log2(hid/8)
        const float* ah = (const float*)d_in[2 + l * 4 + 1];
        const float* ao = (const float*)d_in[2 + l * 4 + 3];

        float* s1 = sball + (size_t)l * SB;
        float* s2 = s1 + NH * NN;
        float* t1 = t12;
        float* t2 = t12 + NN;

        // --- h = x @ Wh  (bf16 out + fused s1/s2), y<->XCD colocate ---
        int nx1 = HD / 64;
        if (l == 0)
            k_mfma<0,3><<<nx1 * 16, 256, 0, stream>>>(xhi, xlo, whh[l], whl[l], nullptr, hh, HD,
                                                      fin, fin, ah, s1, s2, hs, hid, nx1, 1, 0);
        else
            k_mfma<0,2><<<nx1 * 16, 256, 0, stream>>>(xhi, nullptr, whh[l], whl[l], nullptr, hh, HD,
                                                      fin, fin, ah, s1, s2, hs, hid, nx1, 1, 0);

        // per-edge softmax weights (all heads), then pure gather
        k_w<<<NN / 4, 256, 0, stream>>>(s1, s2, rp, ci, wt);
        k_gab<<<NN * NH / 4, 256, 0, stream>>>(hh, wt, rp, ci, ghi, hid, HD, c8sh);

        // --- ho = hcat @ Wo  (split-K partial stores, NO atomics), z<->XCD colocate ---
        int sko = SKwo[l];
        int nx2 = fout / 64;
        k_mfma<1,2><<<nx2 * 16 * sko, 256, 0, stream>>>(ghi, nullptr, woh[l], wol[l], hopart,
                                                        nullptr, fout, HD, HD / sko,
                                                        nullptr, nullptr, nullptr, -1, fout,
                                                        nx2, sko, 1);

        // reduce partials -> ho (fp32) + t1/t2
        k_red<<<NN / 4, 256, 0, stream>>>(hopart, ho, ao, t1, t2, fout, sko);

        // output-head weights + gather
        k_wo<<<NN / 4, 256, 0, stream>>>(t1, t2, rp, ci, wto);
        float* outF = (l == 5) ? (float*)d_out : nullptr;
        int SCtot = (fout / 4 + 63) / 64;      // 1,1,2,1,1,1
        k_gas<<<NN * SCtot / 4, 256, 0, stream>>>(ho, wto, rp, ci, outF, xhi, fout, SCtot);
    }
}

// Round 16
// 522.343 us; speedup vs baseline: 1.0754x; 1.0754x over previous
//
#include <hip/hip_runtime.h>
#include <hip/hip_bf16.h>
#include <math.h>

#define NN 2048          // n_nodes
#define NH 8             // heads
#define LRALPHA 0.2f
#define EMAX (1 << 17)   // edge-capacity stride for weight buffers (nnz ~ 87k)

typedef short bf16x8 __attribute__((ext_vector_type(8)));
typedef float f32x4  __attribute__((ext_vector_type(4)));

static __device__ __forceinline__ float lrelu(float x){ return x > 0.f ? x : LRALPHA * x; }
static __device__ __forceinline__ float elu(float x){ return x > 0.f ? x : expm1f(x); }

static __device__ __forceinline__ unsigned short f2bf(float v){
    unsigned u = __float_as_uint(v);
    unsigned r = (u + 0x7fffu + ((u >> 16) & 1u)) >> 16;
    return (unsigned short)r;
}
static __device__ __forceinline__ float bf2f(unsigned short b){
    return __uint_as_float(((unsigned)b) << 16);
}
static __device__ __forceinline__ float blo(unsigned u){ return __uint_as_float(u << 16); }
static __device__ __forceinline__ float bhi(unsigned u){ return __uint_as_float(u & 0xffff0000u); }

static __device__ __forceinline__ void gload16(const void* g, void* l){
    __builtin_amdgcn_global_load_lds((const __attribute__((address_space(1))) void*)g,
                                     (__attribute__((address_space(3))) void*)l, 16, 0, 0);
}

// accumulate 8 bf16 elems of uint4 u into float A[8] weighted by wv
#define ACC8(A, wv, u) \
    A[0] += wv * blo(u.x); A[1] += wv * bhi(u.x); \
    A[2] += wv * blo(u.y); A[3] += wv * bhi(u.y); \
    A[4] += wv * blo(u.z); A[5] += wv * bhi(u.z); \
    A[6] += wv * blo(u.w); A[7] += wv * bhi(u.w);

// ---------------- CSR build (deterministic, sorted by column) ----------------
__global__ void k_count(const float* __restrict__ adj, int* __restrict__ deg) {
    int gw   = (blockIdx.x * blockDim.x + threadIdx.x) >> 6;
    int lane = threadIdx.x & 63;
    if (gw >= NN) return;
    const float* row = adj + (size_t)gw * NN;
    int cnt = 0;
    for (int j = lane; j < NN; j += 64) cnt += (row[j] > 0.f) ? 1 : 0;
    #pragma unroll
    for (int off = 32; off; off >>= 1) cnt += __shfl_down(cnt, off);
    if (lane == 0) deg[gw] = cnt;
}

__global__ void k_scan(const int* __restrict__ deg, int* __restrict__ rp) {
    __shared__ int a[NN], b[NN];
    int t = threadIdx.x;                       // 1024 threads
    for (int i = t; i < NN; i += 1024) a[i] = deg[i];
    __syncthreads();
    int* src = a; int* dst = b;
    for (int off = 1; off < NN; off <<= 1) {
        for (int i = t; i < NN; i += 1024)
            dst[i] = src[i] + (i >= off ? src[i - off] : 0);
        __syncthreads();
        int* tmp = src; src = dst; dst = tmp;
    }
    for (int i = t; i < NN; i += 1024) rp[i + 1] = src[i];
    if (t == 0) rp[0] = 0;
}

__global__ void k_fill(const float* __restrict__ adj, const int* __restrict__ rp,
                       int* __restrict__ ci) {
    int gw   = (blockIdx.x * blockDim.x + threadIdx.x) >> 6;
    int lane = threadIdx.x & 63;
    if (gw >= NN) return;
    const float* row = adj + (size_t)gw * NN;
    int base = rp[gw];
    for (int j0 = 0; j0 < NN; j0 += 64) {
        bool v = row[j0 + lane] > 0.f;
        unsigned long long m = __ballot(v);
        int pos = __popcll(m & ((1ULL << lane) - 1ULL));
        if (v) ci[base + pos] = j0 + lane;
        base += __popcll(m);
    }
}

// ---------------- split fp32 -> bf16 hi/lo (input x only) ----------------
__global__ void k_split(const float* __restrict__ src, unsigned short* __restrict__ hi,
                        unsigned short* __restrict__ lo, int n4) {
    int i = blockIdx.x * 256 + threadIdx.x;
    if (i >= n4) return;
    float4 v = ((const float4*)src)[i];
    ushort4 h, l;
    h.x = f2bf(v.x); l.x = f2bf(v.x - bf2f(h.x));
    h.y = f2bf(v.y); l.y = f2bf(v.y - bf2f(h.y));
    h.z = f2bf(v.z); l.z = f2bf(v.z - bf2f(h.z));
    h.w = f2bf(v.w); l.w = f2bf(v.w - bf2f(h.w));
    ((ushort4*)hi)[i] = h;
    ((ushort4*)lo)[i] = l;
}

// ------- ALL weight transposes+splits in ONE launch ----
struct TSDesc {
    const float* B[12];
    unsigned short* bh[12];
    unsigned short* bl[12];
    int K[12], Nc[12], hs[12];
    int start[13];
};

__global__ __launch_bounds__(256) void k_tsplit_all(TSDesc d) {
    __shared__ float t[64][65];
    int b = blockIdx.x;
    int s = 0;
    while (b >= d.start[s + 1]) s++;
    int lb = b - d.start[s];
    int K = d.K[s], Nc = d.Nc[s], hs = d.hs[s];
    int tilesX = K >> 6;
    int kb = (lb % tilesX) * 64, cb = (lb / tilesX) * 64;
    const float* B = d.B[s];
    unsigned short* bth = d.bh[s];
    unsigned short* btl = d.bl[s];

    int tid = threadIdx.x;
    #pragma unroll
    for (int i = 0; i < 16; i++) {
        int idx = i * 256 + tid;
        int kk = idx >> 6, cc = idx & 63;
        int c = cb + cc, k = kb + kk;
        float v;
        if (hs < 0) v = B[(size_t)k * Nc + c];
        else {
            int hid = 1 << hs; int head = c >> hs; int dd = c & (hid - 1);
            v = B[((size_t)head * K + k) * hid + dd];
        }
        t[kk][cc] = v;
    }
    __syncthreads();
    #pragma unroll
    for (int i = 0; i < 16; i++) {
        int idx = i * 256 + tid;
        int cc = idx >> 6, kk = idx & 63;
        float v = t[kk][cc];
        unsigned short h = f2bf(v);
        size_t o = (size_t)(cb + cc) * K + kb + kk;
        bth[o] = h;
        btl[o] = f2bf(v - bf2f(h));
    }
}

// ---------- split-bf16 MFMA GEMM, 256 threads, 128(M) x 64(N) tile ----------
// (round-12 proven config)
template<int OUT, int NT>
__global__ __launch_bounds__(256) void k_mfma(
    const unsigned short* __restrict__ Ah, const unsigned short* __restrict__ Al,
    const unsigned short* __restrict__ Bh, const unsigned short* __restrict__ Bl,
    float* __restrict__ Cf, unsigned short* __restrict__ Cb, int Nc, int K, int Kc,
    const float* __restrict__ avec, float* __restrict__ sg1, float* __restrict__ sg2,
    int hs, int aoff, int nx, int nz, int zcol)
{
    constexpr int ALB = 4096;                       // ushort units (NT=3 only)
    constexpr int BHB = (NT == 3) ? 8192 : 4096;
    constexpr int BLB = BHB + 2048;
    __shared__ unsigned short lds[(NT == 3) ? 12288 : 8192];  // 24KB / 16KB
    int tid = threadIdx.x, lane = tid & 63, w = tid >> 6;

    int g = blockIdx.x;
    int xcd = g & 7, q = g >> 3;
    int x, y, z;
    if (zcol) {
        int zper = nz >> 3;
        z = xcd + 8 * (q % zper);
        int r = q / zper;
        int nxy = nx * 16;
        int r2 = r + xcd * (nxy >> 3); if (r2 >= nxy) r2 -= nxy;
        x = r2 % nx; y = r2 / nx;
    } else {
        y = xcd + 8 * (q & 1);
        x = q >> 1; z = 0;
    }
    int m0 = y * 128, n0 = x * 64;
    int kbeg = z * Kc;

    int ra0 = tid >> 2;       int ga0 = ((tid & 3) - (ra0 >> 1)) & 3;
    int ra1 = 64 + (tid >> 2); int ga1 = ((tid & 3) - (ra1 >> 1)) & 3;
    int rb  = tid >> 2;       int gb  = ((tid & 3) - (rb >> 1)) & 3;
    const unsigned short* pAh0 = Ah + (size_t)(m0 + ra0) * K + kbeg + ga0 * 8;
    const unsigned short* pAh1 = Ah + (size_t)(m0 + ra1) * K + kbeg + ga1 * 8;
    const unsigned short* pAl0 = (NT == 3) ? Al + (size_t)(m0 + ra0) * K + kbeg + ga0 * 8 : nullptr;
    const unsigned short* pAl1 = (NT == 3) ? Al + (size_t)(m0 + ra1) * K + kbeg + ga1 * 8 : nullptr;
    const unsigned short* pBh  = Bh + (size_t)(n0 + rb) * K + kbeg + gb * 8;
    const unsigned short* pBl  = Bl + (size_t)(n0 + rb) * K + kbeg + gb * 8;
    unsigned short* dA0 = &lds[w * 512];
    unsigned short* dA1 = &lds[2048 + w * 512];
    unsigned short* dB  = &lds[BHB + w * 512];

    int wr = w >> 1, wc = w & 1;
    int offA[4], offB[2];
    #pragma unroll
    for (int m = 0; m < 4; m++) {
        int row = wr * 64 + m * 16 + (lane & 15); int gg = lane >> 4;
        offA[m] = (row * 4 + ((gg + (row >> 1)) & 3)) * 8;
    }
    #pragma unroll
    for (int n = 0; n < 2; n++) {
        int row = wc * 32 + n * 16 + (lane & 15); int gg = lane >> 4;
        offB[n] = (row * 4 + ((gg + (row >> 1)) & 3)) * 8;
    }

    f32x4 acc[4][2];
    #pragma unroll
    for (int m = 0; m < 4; m++)
        #pragma unroll
        for (int n = 0; n < 2; n++) acc[m][n] = (f32x4){0.f, 0.f, 0.f, 0.f};

    int nk = Kc >> 5;
    for (int ks = 0; ks < nk; ks++) {
        gload16(pAh0, dA0);
        gload16(pAh1, dA1);
        if (NT == 3) { gload16(pAl0, dA0 + ALB); gload16(pAl1, dA1 + ALB); }
        gload16(pBh, dB);
        gload16(pBl, dB + 2048);
        pAh0 += 32; pAh1 += 32;
        if (NT == 3) { pAl0 += 32; pAl1 += 32; }
        pBh += 32; pBl += 32;
        __syncthreads();
        bf16x8 ah[4], al[4], bh[2], bl[2];
        #pragma unroll
        for (int m = 0; m < 4; m++) {
            ah[m] = *(const bf16x8*)&lds[offA[m]];
            if (NT == 3) al[m] = *(const bf16x8*)&lds[ALB + offA[m]];
        }
        #pragma unroll
        for (int n = 0; n < 2; n++) {
            bh[n] = *(const bf16x8*)&lds[BHB + offB[n]];
            bl[n] = *(const bf16x8*)&lds[BLB + offB[n]];
        }
        #pragma unroll
        for (int m = 0; m < 4; m++)
            #pragma unroll
            for (int n = 0; n < 2; n++) {
                acc[m][n] = __builtin_amdgcn_mfma_f32_16x16x32_bf16(ah[m], bh[n], acc[m][n], 0, 0, 0);
                if (NT == 3)
                    acc[m][n] = __builtin_amdgcn_mfma_f32_16x16x32_bf16(al[m], bh[n], acc[m][n], 0, 0, 0);
                acc[m][n] = __builtin_amdgcn_mfma_f32_16x16x32_bf16(ah[m], bl[n], acc[m][n], 0, 0, 0);
            }
        __syncthreads();
    }

    size_t pbase = (size_t)z * NN * Nc;
    #pragma unroll
    for (int m = 0; m < 4; m++)
        #pragma unroll
        for (int n = 0; n < 2; n++) {
            int row = m0 + wr * 64 + m * 16 + (lane >> 4) * 4;
            int col = n0 + wc * 32 + n * 16 + (lane & 15);
            #pragma unroll
            for (int r = 0; r < 4; r++) {
                float v = acc[m][n][r];
                if (OUT == 0) Cb[(size_t)(row + r) * Nc + col] = f2bf(v);
                else          Cf[pbase + (size_t)(row + r) * Nc + col] = v;
            }
        }

    if (OUT == 0) {
        int head = (hs >= 0) ? (n0 >> hs) : 0;
        const float* ab = avec + head * 2 * aoff;
        float av1[2], av2[2];
        int colbase = n0 + wc * 32 + (lane & 15);
        #pragma unroll
        for (int n = 0; n < 2; n++) {
            int c = colbase + n * 16;
            int dd = (hs >= 0) ? (c & (aoff - 1)) : c;
            av1[n] = ab[dd];
            av2[n] = ab[dd + aoff];
        }
        #pragma unroll
        for (int m = 0; m < 4; m++)
            #pragma unroll
            for (int r = 0; r < 4; r++) {
                float p1 = 0.f, p2 = 0.f;
                #pragma unroll
                for (int n = 0; n < 2; n++) {
                    float v = acc[m][n][r];
                    p1 += v * av1[n];
                    p2 += v * av2[n];
                }
                #pragma unroll
                for (int o = 1; o < 16; o <<= 1) {
                    p1 += __shfl_xor(p1, o);
                    p2 += __shfl_xor(p2, o);
                }
                if ((lane & 15) == 0) {
                    int row = m0 + wr * 64 + m * 16 + (lane >> 4) * 4 + r;
                    atomicAdd(&sg1[head * NN + row], p1);
                    atomicAdd(&sg2[head * NN + row], p2);
                }
            }
    }
}

// ------- split-K reducer: 4 waves/block, one row per wave -------
__global__ __launch_bounds__(256) void k_red(
    const float* __restrict__ part, float* __restrict__ ho,
    const float* __restrict__ ao, float* __restrict__ t1, float* __restrict__ t2,
    int fout, int sko)
{
    int wid = threadIdx.x >> 6;
    int lane = threadIdx.x & 63;
    int row = blockIdx.x * 4 + wid;
    int C4 = fout >> 2;
    const float4* p4 = (const float4*)part;
    size_t stride4 = (size_t)NN * C4;
    float d1 = 0.f, d2 = 0.f;
    for (int c = lane; c < C4; c += 64) {
        size_t o = (size_t)row * C4 + c;
        float4 s = p4[o];
        for (int zz = 1; zz < sko; zz++) {
            float4 v = p4[o + (size_t)zz * stride4];
            s.x += v.x; s.y += v.y; s.z += v.z; s.w += v.w;
        }
        ((float4*)ho)[o] = s;
        int cc = c * 4;
        d1 += s.x * ao[cc]        + s.y * ao[cc + 1]
            + s.z * ao[cc + 2]    + s.w * ao[cc + 3];
        d2 += s.x * ao[fout + cc]     + s.y * ao[fout + cc + 1]
            + s.z * ao[fout + cc + 2] + s.w * ao[fout + cc + 3];
    }
    #pragma unroll
    for (int o = 32; o; o >>= 1) { d1 += __shfl_xor(d1, o); d2 += __shfl_xor(d2, o); }
    if (lane == 0) { t1[row] = d1; t2[row] = d2; }
}

// ------- per-edge softmax weights, ALL heads in parallel: wave per node -------
// 8 lane-groups of 8; group = head; sublane strides edges; e-values in registers.
__global__ __launch_bounds__(256) void k_w(
    const float* __restrict__ s1, const float* __restrict__ s2,
    const int* __restrict__ rp, const int* __restrict__ ci,
    float* __restrict__ wt)
{
    int wid = threadIdx.x >> 6, lane = threadIdx.x & 63;
    int i = blockIdx.x * 4 + wid;
    int h = lane >> 3, s = lane & 7;
    int base = rp[i], deg = rp[i + 1] - base;
    float s1i = s1[h * NN + i];
    const float* s2h = s2 + h * NN;
    float* wth = wt + (size_t)h * EMAX + base;

    if (deg <= 128) {
        float ev[16];
        float m = -1e30f;
        #pragma unroll
        for (int c = 0; c < 16; c++) {
            int k = s + c * 8;
            float e = -1e30f;
            if (k < deg) e = lrelu(s1i + s2h[ci[base + k]]);
            ev[c] = e;
            m = fmaxf(m, e);
        }
        #pragma unroll
        for (int o = 1; o < 8; o <<= 1) m = fmaxf(m, __shfl_xor(m, o));
        float sum = 0.f;
        #pragma unroll
        for (int c = 0; c < 16; c++) { ev[c] = expf(ev[c] - m); sum += ev[c]; }
        #pragma unroll
        for (int o = 1; o < 8; o <<= 1) sum += __shfl_xor(sum, o);
        float inv = 1.f / sum;
        #pragma unroll
        for (int c = 0; c < 16; c++) {
            int k = s + c * 8;
            if (k < deg) wth[k] = ev[c] * inv;
        }
    } else {
        // generic 3-pass fallback (never hit for this graph; correctness only)
        float m = -1e30f;
        for (int k = s; k < deg; k += 8) m = fmaxf(m, lrelu(s1i + s2h[ci[base + k]]));
        #pragma unroll
        for (int o = 1; o < 8; o <<= 1) m = fmaxf(m, __shfl_xor(m, o));
        float sum = 0.f;
        for (int k = s; k < deg; k += 8) sum += expf(lrelu(s1i + s2h[ci[base + k]]) - m);
        #pragma unroll
        for (int o = 1; o < 8; o <<= 1) sum += __shfl_xor(sum, o);
        float inv = 1.f / sum;
        for (int k = s; k < deg; k += 8)
            wth[k] = expf(lrelu(s1i + s2h[ci[base + k]]) - m) * inv;
    }
}

// ------- per-edge softmax weights, single output head: 8 nodes per wave -------
__global__ __launch_bounds__(256) void k_wo(
    const float* __restrict__ t1, const float* __restrict__ t2,
    const int* __restrict__ rp, const int* __restrict__ ci,
    float* __restrict__ wto)
{
    int wid = threadIdx.x >> 6, lane = threadIdx.x & 63;
    int g = lane >> 3, s = lane & 7;
    int i = (blockIdx.x * 4 + wid) * 8 + g;
    int base = rp[i], deg = rp[i + 1] - base;
    float s1i = t1[i];

    if (deg <= 128) {
        float ev[16];
        float m = -1e30f;
        #pragma unroll
        for (int c = 0; c < 16; c++) {
            int k = s + c * 8;
            float e = -1e30f;
            if (k < deg) e = lrelu(s1i + t2[ci[base + k]]);
            ev[c] = e;
            m = fmaxf(m, e);
        }
        #pragma unroll
        for (int o = 1; o < 8; o <<= 1) m = fmaxf(m, __shfl_xor(m, o));
        float sum = 0.f;
        #pragma unroll
        for (int c = 0; c < 16; c++) { ev[c] = expf(ev[c] - m); sum += ev[c]; }
        #pragma unroll
        for (int o = 1; o < 8; o <<= 1) sum += __shfl_xor(sum, o);
        float inv = 1.f / sum;
        #pragma unroll
        for (int c = 0; c < 16; c++) {
            int k = s + c * 8;
            if (k < deg) wto[base + k] = ev[c] * inv;
        }
    } else {
        float m = -1e30f;
        for (int k = s; k < deg; k += 8) m = fmaxf(m, lrelu(s1i + t2[ci[base + k]]));
        #pragma unroll
        for (int o = 1; o < 8; o <<= 1) m = fmaxf(m, __shfl_xor(m, o));
        float sum = 0.f;
        for (int k = s; k < deg; k += 8) sum += expf(lrelu(s1i + t2[ci[base + k]]) - m);
        #pragma unroll
        for (int o = 1; o < 8; o <<= 1) sum += __shfl_xor(sum, o);
        float inv = 1.f / sum;
        for (int k = s; k < deg; k += 8)
            wto[base + k] = expf(lrelu(s1i + t2[ci[base + k]]) - m) * inv;
    }
}

// ------------- BIG gather: 4 waves/block, one (node,head) per wave, pure gather -------------
// 4-way unrolled with 4 persistent accumulator sets (weights pre-normalized; no rescale).
__global__ __launch_bounds__(256) void k_gab(
    const unsigned short* __restrict__ hh, const float* __restrict__ wt,
    const int* __restrict__ rp, const int* __restrict__ ci,
    unsigned short* __restrict__ outH, int hid, int HD, int c8sh)
{
    __shared__ float    wls[256];
    __shared__ unsigned cls[256];

    int tid = threadIdx.x;
    int wid = tid >> 6;
    int lane = tid & 63;
    int head = blockIdx.x & (NH - 1);
    int i    = (blockIdx.x >> 3) * 4 + wid;
    float* wlsw = wls + wid * 64;
    unsigned* clsw = cls + wid * 64;

    int base = rp[i], deg = rp[i + 1] - base;
    const float* wth = wt + (size_t)head * EMAX + base;

    int C8  = 1 << c8sh;                  // ushort8 cols per head slice (16/32/64)
    int G   = 64 >> c8sh;                 // neighbor groups (4/2/1)
    int col = lane & (C8 - 1);
    int grp = lane >> c8sh;

    const uint4* h4 = (const uint4*)hh;
    unsigned hoff8 = (unsigned)(head * hid) >> 3;
    unsigned ld8   = (unsigned)HD >> 3;

    float aA[8], qB[8], rC[8], sD[8];
    #pragma unroll
    for (int e = 0; e < 8; e++) { aA[e] = 0.f; qB[e] = 0.f; rC[e] = 0.f; sD[e] = 0.f; }

    for (int k0 = 0; k0 < deg; k0 += 64) {
        int n = min(64, deg - k0);
        if (lane < n) {
            wlsw[lane] = wth[k0 + lane];
            clsw[lane] = (unsigned)ci[base + k0 + lane] * ld8 + hoff8;
        }
        // wave-synchronous LDS (single wave writes+reads; no barrier needed)
        int k = grp;
        for (; k + 3 * G < n; k += 4 * G) {
            float w0 = wlsw[k], w1 = wlsw[k + G], w2 = wlsw[k + 2 * G], w3 = wlsw[k + 3 * G];
            uint4 u0 = h4[clsw[k]         + col];
            uint4 u1 = h4[clsw[k + G]     + col];
            uint4 u2 = h4[clsw[k + 2 * G] + col];
            uint4 u3 = h4[clsw[k + 3 * G] + col];
            ACC8(aA, w0, u0);
            ACC8(qB, w1, u1);
            ACC8(rC, w2, u2);
            ACC8(sD, w3, u3);
        }
        for (; k < n; k += G) {
            float w0 = wlsw[k];
            uint4 u0 = h4[clsw[k] + col];
            ACC8(aA, w0, u0);
        }
    }

    #pragma unroll
    for (int e = 0; e < 8; e++) aA[e] += qB[e] + rC[e] + sD[e];

    // cross-group reduction via register shuffles (G=1: none)
    #pragma unroll
    for (int m = 32; m >= 1; m >>= 1) {
        if (m >= C8) {
            #pragma unroll
            for (int e = 0; e < 8; e++) aA[e] += __shfl_xor(aA[e], m);
        }
    }

    if (grp == 0) {
        unsigned short hh_[8];
        #pragma unroll
        for (int e = 0; e < 8; e++) hh_[e] = f2bf(elu(aA[e]));
        size_t ob = ((size_t)i * HD + head * hid) >> 3;
        uint4 ph;
        ph.x = (unsigned)hh_[0] | ((unsigned)hh_[1] << 16);
        ph.y = (unsigned)hh_[2] | ((unsigned)hh_[3] << 16);
        ph.z = (unsigned)hh_[4] | ((unsigned)hh_[5] << 16);
        ph.w = (unsigned)hh_[6] | ((unsigned)hh_[7] << 16);
        ((uint4*)outH)[ob + col] = ph;
    }
}

// ------------- SMALL gather: 4 waves/block, one (node,slice) per wave -------------
__global__ __launch_bounds__(256) void k_gas(
    const float* __restrict__ hsrc, const float* __restrict__ wto,
    const int* __restrict__ rp, const int* __restrict__ ci,
    float* __restrict__ outF, unsigned short* __restrict__ outH,
    int fout, int SCtot)
{
    __shared__ float    wls[256];
    __shared__ unsigned cls[256];

    int tid = threadIdx.x;
    int wid = tid >> 6;
    int lane = tid & 63;
    int task = blockIdx.x * 4 + wid;
    int i   = task / SCtot;
    int sc  = task - i * SCtot;
    float* wlsw = wls + wid * 64;
    unsigned* clsw = cls + wid * 64;

    int base = rp[i], deg = rp[i + 1] - base;

    int C4tot = fout >> 2;
    int soff  = sc * 64;
    int C4s   = min(64, C4tot - soff);        // 64 or 32 (pow2)
    int c4sh  = 31 - __clz(C4s);
    int col = lane & (C4s - 1);
    int grp = lane >> c4sh;
    int G   = 64 >> c4sh;

    const float4* h4 = (const float4*)hsrc;
    unsigned ld4 = (unsigned)fout >> 2;

    float4 acc = make_float4(0.f, 0.f, 0.f, 0.f);
    float4 q   = make_float4(0.f, 0.f, 0.f, 0.f);

    for (int k0 = 0; k0 < deg; k0 += 64) {
        int n = min(64, deg - k0);
        if (lane < n) {
            wlsw[lane] = wto[base + k0 + lane];
            clsw[lane] = (unsigned)ci[base + k0 + lane] * ld4 + soff;
        }
        int k = grp;
        for (; k + G < n; k += 2 * G) {
            float w0 = wlsw[k], w1 = wlsw[k + G];
            float4 h0 = h4[clsw[k]     + col];
            float4 h1 = h4[clsw[k + G] + col];
            acc.x += w0 * h0.x; acc.y += w0 * h0.y; acc.z += w0 * h0.z; acc.w += w0 * h0.w;
            q.x   += w1 * h1.x; q.y   += w1 * h1.y; q.z   += w1 * h1.z; q.w   += w1 * h1.w;
        }
        if (k < n) {
            float w0 = wlsw[k];
            float4 h0 = h4[clsw[k] + col];
            acc.x += w0 * h0.x; acc.y += w0 * h0.y; acc.z += w0 * h0.z; acc.w += w0 * h0.w;
        }
    }
    acc.x += q.x; acc.y += q.y; acc.z += q.z; acc.w += q.w;

    #pragma unroll
    for (int o = 64; o > 1; o >>= 1) {
        if (o > C4s) {
            int m = o >> 1;
            acc.x += __shfl_xor(acc.x, m); acc.y += __shfl_xor(acc.y, m);
            acc.z += __shfl_xor(acc.z, m); acc.w += __shfl_xor(acc.w, m);
        }
    }

    if (grp == 0) {
        float4 val;
        val.x = elu(acc.x); val.y = elu(acc.y);
        val.z = elu(acc.z); val.w = elu(acc.w);
        size_t o4 = (size_t)i * ld4 + soff + col;
        if (outF) ((float4*)outF)[o4] = val;
        ushort4 h;
        h.x = f2bf(val.x); h.y = f2bf(val.y);
        h.z = f2bf(val.z); h.w = f2bf(val.w);
        ((ushort4*)outH)[o4] = h;
    }
}

// ---------------- host driver ----------------
extern "C" void kernel_launch(void* const* d_in, const int* in_sizes, int n_in,
                              void* d_out, int out_size, void* d_ws, size_t ws_size,
                              hipStream_t stream)
{
    const float* x   = (const float*)d_in[0];
    const float* adj = (const float*)d_in[1];
    struct L { int fin, hid, fout; };
    const L dims[6] = {{256,128,128},{128,256,256},{256,512,384},
                       {384,512,256},{256,256,128},{128,128,256}};
    const int SKwo[6] = {16, 8, 8, 8, 16, 8};
    const int SB = 2 * NH * NN;              // per-layer s1/s2 floats

    char* ws = (char*)d_ws;
    size_t off = 0;
    auto alloc = [&](size_t bytes) -> void* {
        void* p = ws + off;
        off = (off + bytes + 255) & ~(size_t)255;
        return p;
    };
    int*   rp   = (int*)alloc((NN + 1) * sizeof(int));
    int*   deg  = (int*)alloc(NN * sizeof(int));
    int*   ci   = (int*)alloc((size_t)(1 << 20) * sizeof(int));
    unsigned short* hh  = (unsigned short*)alloc((size_t)NN * 4096 * 2);  // bf16 h
    unsigned short* ghi = (unsigned short*)alloc((size_t)NN * 4096 * 2);  // bf16 hcat
    unsigned short* xhi = (unsigned short*)alloc((size_t)NN * 512 * 2);
    unsigned short* xlo = (unsigned short*)alloc((size_t)NN * 512 * 2);
    float* sball  = (float*)alloc((size_t)6 * SB * sizeof(float));        // all-layer s1/s2
    float* hopart = (float*)alloc((size_t)NN * 3072 * sizeof(float));     // split-K partials
    float* ho     = (float*)alloc((size_t)NN * 384 * sizeof(float));      // reduced ho (fp32)
    float* t12    = (float*)alloc((size_t)2 * NN * sizeof(float));        // t1/t2
    float* wt     = (float*)alloc((size_t)NH * EMAX * sizeof(float));     // per-head edge weights
    float* wto    = (float*)alloc((size_t)EMAX * sizeof(float));          // output-head edge weights

    unsigned short* whh[6]; unsigned short* whl[6];
    unsigned short* woh[6]; unsigned short* wol[6];
    TSDesc td;
    int nblk = 0;
    for (int l = 0; l < 6; l++) {
        int fin = dims[l].fin, hid = dims[l].hid, fout = dims[l].fout;
        int HD = NH * hid;
        size_t szWh = (size_t)fin * HD, szWo = (size_t)HD * fout;
        whh[l] = (unsigned short*)alloc(szWh * 2);
        whl[l] = (unsigned short*)alloc(szWh * 2);
        woh[l] = (unsigned short*)alloc(szWo * 2);
        wol[l] = (unsigned short*)alloc(szWo * 2);
        int hs = (hid == 128) ? 7 : (hid == 256) ? 8 : 9;
        td.B[2*l] = (const float*)d_in[2 + l * 4 + 0];
        td.bh[2*l] = whh[l]; td.bl[2*l] = whl[l];
        td.K[2*l] = fin; td.Nc[2*l] = HD; td.hs[2*l] = hs;
        td.start[2*l] = nblk; nblk += (fin / 64) * (HD / 64);
        td.B[2*l+1] = (const float*)d_in[2 + l * 4 + 2];
        td.bh[2*l+1] = woh[l]; td.bl[2*l+1] = wol[l];
        td.K[2*l+1] = HD; td.Nc[2*l+1] = fout; td.hs[2*l+1] = -1;
        td.start[2*l+1] = nblk; nblk += (HD / 64) * (fout / 64);
    }
    td.start[12] = nblk;

    // ---- front matter: one memset (s1/s2 only) + CSR + x split + weight splits ----
    hipMemsetAsync(sball, 0, (size_t)6 * SB * sizeof(float), stream);
    k_count<<<NN / 4, 256, 0, stream>>>(adj, deg);
    k_scan <<<1, 1024, 0, stream>>>(deg, rp);
    k_fill <<<NN / 4, 256, 0, stream>>>(adj, rp, ci);
    k_split<<<(NN * 256 / 4 + 255) / 256, 256, 0, stream>>>(x, xhi, xlo, NN * 256 / 4);
    k_tsplit_all<<<nblk, 256, 0, stream>>>(td);

    for (int l = 0; l < 6; l++) {
        int fin = dims[l].fin, hid = dims[l].hid, fout = dims[l].fout;
        int HD = NH * hid;
        int hs = (hid == 128) ? 7 : (hid == 256) ? 8 : 9;
        int c8sh = hs - 3;                     // log2(hid/8)
        const float* ah = (const float*)d_in[2 + l * 4 + 1];
        const float* ao = (const float*)d_in[2 + l * 4 + 3];

        float* s1 = sball + (size_t)l * SB;
        float* s2 = s1 + NH * NN;
        float* t1 = t12;
        float* t2 = t12 + NN;

        // --- h = x @ Wh  (bf16 out + fused s1/s2), y<->XCD colocate ---
        int nx1 = HD / 64;
        if (l == 0)
            k_mfma<0,3><<<nx1 * 16, 256, 0, stream>>>(xhi, xlo, whh[l], whl[l], nullptr, hh, HD,
                                                      fin, fin, ah, s1, s2, hs, hid, nx1, 1, 0);
        else
            k_mfma<0,2><<<nx1 * 16, 256, 0, stream>>>(xhi, nullptr, whh[l], whl[l], nullptr, hh, HD,
                                                      fin, fin, ah, s1, s2, hs, hid, nx1, 1, 0);

        // per-edge softmax weights (head-parallel), then pure gather
        k_w<<<NN / 4, 256, 0, stream>>>(s1, s2, rp, ci, wt);
        k_gab<<<NN * NH / 4, 256, 0, stream>>>(hh, wt, rp, ci, ghi, hid, HD, c8sh);

        // --- ho = hcat @ Wo  (split-K partial stores, NO atomics), z<->XCD colocate ---
        int sko = SKwo[l];
        int nx2 = fout / 64;
        k_mfma<1,2><<<nx2 * 16 * sko, 256, 0, stream>>>(ghi, nullptr, woh[l], wol[l], hopart,
                                                        nullptr, fout, HD, HD / sko,
                                                        nullptr, nullptr, nullptr, -1, fout,
                                                        nx2, sko, 1);

        // reduce partials -> ho (fp32) + t1/t2
        k_red<<<NN / 4, 256, 0, stream>>>(hopart, ho, ao, t1, t2, fout, sko);

        // output-head weights + gather
        k_wo<<<NN / 32, 256, 0, stream>>>(t1, t2, rp, ci, wto);
        float* outF = (l == 5) ? (float*)d_out : nullptr;
        int SCtot = (fout / 4 + 63) / 64;      // 1,1,2,1,1,1
        k_gas<<<NN * SCtot / 4, 256, 0, stream>>>(ho, wto, rp, ci, outF, xhi, fout, SCtot);
    }
}

// Round 17
// 484.944 us; speedup vs baseline: 1.1584x; 1.0771x over previous
//
#include <hip/hip_runtime.h>
#include <hip/hip_bf16.h>
#include <math.h>

#define NN 2048          // n_nodes
#define NH 8             // heads
#define LRALPHA 0.2f

typedef short bf16x8 __attribute__((ext_vector_type(8)));
typedef float f32x4  __attribute__((ext_vector_type(4)));

static __device__ __forceinline__ float lrelu(float x){ return x > 0.f ? x : LRALPHA * x; }
static __device__ __forceinline__ float elu(float x){ return x > 0.f ? x : expm1f(x); }

static __device__ __forceinline__ unsigned short f2bf(float v){
    unsigned u = __float_as_uint(v);
    unsigned r = (u + 0x7fffu + ((u >> 16) & 1u)) >> 16;
    return (unsigned short)r;
}
static __device__ __forceinline__ float bf2f(unsigned short b){
    return __uint_as_float(((unsigned)b) << 16);
}
static __device__ __forceinline__ float blo(unsigned u){ return __uint_as_float(u << 16); }
static __device__ __forceinline__ float bhi(unsigned u){ return __uint_as_float(u & 0xffff0000u); }

static __device__ __forceinline__ void gload16(const void* g, void* l){
    __builtin_amdgcn_global_load_lds((const __attribute__((address_space(1))) void*)g,
                                     (__attribute__((address_space(3))) void*)l, 16, 0, 0);
}

// accumulate 8 bf16 elems of uint4 u into float A[8] weighted by wv
#define ACC8(A, wv, u) \
    A[0] += wv * blo(u.x); A[1] += wv * bhi(u.x); \
    A[2] += wv * blo(u.y); A[3] += wv * bhi(u.y); \
    A[4] += wv * blo(u.z); A[5] += wv * bhi(u.z); \
    A[6] += wv * blo(u.w); A[7] += wv * bhi(u.w);

// ---------------- CSR build (deterministic, sorted by column) ----------------
__global__ void k_count(const float* __restrict__ adj, int* __restrict__ deg) {
    int gw   = (blockIdx.x * blockDim.x + threadIdx.x) >> 6;
    int lane = threadIdx.x & 63;
    if (gw >= NN) return;
    const float* row = adj + (size_t)gw * NN;
    int cnt = 0;
    for (int j = lane; j < NN; j += 64) cnt += (row[j] > 0.f) ? 1 : 0;
    #pragma unroll
    for (int off = 32; off; off >>= 1) cnt += __shfl_down(cnt, off);
    if (lane == 0) deg[gw] = cnt;
}

__global__ void k_scan(const int* __restrict__ deg, int* __restrict__ rp) {
    __shared__ int a[NN], b[NN];
    int t = threadIdx.x;                       // 1024 threads
    for (int i = t; i < NN; i += 1024) a[i] = deg[i];
    __syncthreads();
    int* src = a; int* dst = b;
    for (int off = 1; off < NN; off <<= 1) {
        for (int i = t; i < NN; i += 1024)
            dst[i] = src[i] + (i >= off ? src[i - off] : 0);
        __syncthreads();
        int* tmp = src; src = dst; dst = tmp;
    }
    for (int i = t; i < NN; i += 1024) rp[i + 1] = src[i];
    if (t == 0) rp[0] = 0;
}

__global__ void k_fill(const float* __restrict__ adj, const int* __restrict__ rp,
                       int* __restrict__ ci) {
    int gw   = (blockIdx.x * blockDim.x + threadIdx.x) >> 6;
    int lane = threadIdx.x & 63;
    if (gw >= NN) return;
    const float* row = adj + (size_t)gw * NN;
    int base = rp[gw];
    for (int j0 = 0; j0 < NN; j0 += 64) {
        bool v = row[j0 + lane] > 0.f;
        unsigned long long m = __ballot(v);
        int pos = __popcll(m & ((1ULL << lane) - 1ULL));
        if (v) ci[base + pos] = j0 + lane;
        base += __popcll(m);
    }
}

// ---------------- split fp32 -> bf16 hi/lo (input x only) ----------------
__global__ void k_split(const float* __restrict__ src, unsigned short* __restrict__ hi,
                        unsigned short* __restrict__ lo, int n4) {
    int i = blockIdx.x * 256 + threadIdx.x;
    if (i >= n4) return;
    float4 v = ((const float4*)src)[i];
    ushort4 h, l;
    h.x = f2bf(v.x); l.x = f2bf(v.x - bf2f(h.x));
    h.y = f2bf(v.y); l.y = f2bf(v.y - bf2f(h.y));
    h.z = f2bf(v.z); l.z = f2bf(v.z - bf2f(h.z));
    h.w = f2bf(v.w); l.w = f2bf(v.w - bf2f(h.w));
    ((ushort4*)hi)[i] = h;
    ((ushort4*)lo)[i] = l;
}

// ------- ALL weight transposes+splits in ONE launch ----
struct TSDesc {
    const float* B[12];
    unsigned short* bh[12];
    unsigned short* bl[12];
    int K[12], Nc[12], hs[12];
    int start[13];
};

__global__ __launch_bounds__(256) void k_tsplit_all(TSDesc d) {
    __shared__ float t[64][65];
    int b = blockIdx.x;
    int s = 0;
    while (b >= d.start[s + 1]) s++;
    int lb = b - d.start[s];
    int K = d.K[s], Nc = d.Nc[s], hs = d.hs[s];
    int tilesX = K >> 6;
    int kb = (lb % tilesX) * 64, cb = (lb / tilesX) * 64;
    const float* B = d.B[s];
    unsigned short* bth = d.bh[s];
    unsigned short* btl = d.bl[s];

    int tid = threadIdx.x;
    #pragma unroll
    for (int i = 0; i < 16; i++) {
        int idx = i * 256 + tid;
        int kk = idx >> 6, cc = idx & 63;
        int c = cb + cc, k = kb + kk;
        float v;
        if (hs < 0) v = B[(size_t)k * Nc + c];
        else {
            int hid = 1 << hs; int head = c >> hs; int dd = c & (hid - 1);
            v = B[((size_t)head * K + k) * hid + dd];
        }
        t[kk][cc] = v;
    }
    __syncthreads();
    #pragma unroll
    for (int i = 0; i < 16; i++) {
        int idx = i * 256 + tid;
        int cc = idx >> 6, kk = idx & 63;
        float v = t[kk][cc];
        unsigned short h = f2bf(v);
        size_t o = (size_t)(cb + cc) * K + kb + kk;
        bth[o] = h;
        btl[o] = f2bf(v - bf2f(h));
    }
}

// ---------- split-bf16 MFMA GEMM, 256 threads, 128(M) x 64(N) tile ----------
// (round-12 proven config)
template<int OUT, int NT>
__global__ __launch_bounds__(256) void k_mfma(
    const unsigned short* __restrict__ Ah, const unsigned short* __restrict__ Al,
    const unsigned short* __restrict__ Bh, const unsigned short* __restrict__ Bl,
    float* __restrict__ Cf, unsigned short* __restrict__ Cb, int Nc, int K, int Kc,
    const float* __restrict__ avec, float* __restrict__ sg1, float* __restrict__ sg2,
    int hs, int aoff, int nx, int nz, int zcol)
{
    constexpr int ALB = 4096;                       // ushort units (NT=3 only)
    constexpr int BHB = (NT == 3) ? 8192 : 4096;
    constexpr int BLB = BHB + 2048;
    __shared__ unsigned short lds[(NT == 3) ? 12288 : 8192];  // 24KB / 16KB
    int tid = threadIdx.x, lane = tid & 63, w = tid >> 6;

    int g = blockIdx.x;
    int xcd = g & 7, q = g >> 3;
    int x, y, z;
    if (zcol) {
        int zper = nz >> 3;
        z = xcd + 8 * (q % zper);
        int r = q / zper;
        int nxy = nx * 16;
        int r2 = r + xcd * (nxy >> 3); if (r2 >= nxy) r2 -= nxy;
        x = r2 % nx; y = r2 / nx;
    } else {
        y = xcd + 8 * (q & 1);
        x = q >> 1; z = 0;
    }
    int m0 = y * 128, n0 = x * 64;
    int kbeg = z * Kc;

    int ra0 = tid >> 2;       int ga0 = ((tid & 3) - (ra0 >> 1)) & 3;
    int ra1 = 64 + (tid >> 2); int ga1 = ((tid & 3) - (ra1 >> 1)) & 3;
    int rb  = tid >> 2;       int gb  = ((tid & 3) - (rb >> 1)) & 3;
    const unsigned short* pAh0 = Ah + (size_t)(m0 + ra0) * K + kbeg + ga0 * 8;
    const unsigned short* pAh1 = Ah + (size_t)(m0 + ra1) * K + kbeg + ga1 * 8;
    const unsigned short* pAl0 = (NT == 3) ? Al + (size_t)(m0 + ra0) * K + kbeg + ga0 * 8 : nullptr;
    const unsigned short* pAl1 = (NT == 3) ? Al + (size_t)(m0 + ra1) * K + kbeg + ga1 * 8 : nullptr;
    const unsigned short* pBh  = Bh + (size_t)(n0 + rb) * K + kbeg + gb * 8;
    const unsigned short* pBl  = Bl + (size_t)(n0 + rb) * K + kbeg + gb * 8;
    unsigned short* dA0 = &lds[w * 512];
    unsigned short* dA1 = &lds[2048 + w * 512];
    unsigned short* dB  = &lds[BHB + w * 512];

    int wr = w >> 1, wc = w & 1;
    int offA[4], offB[2];
    #pragma unroll
    for (int m = 0; m < 4; m++) {
        int row = wr * 64 + m * 16 + (lane & 15); int gg = lane >> 4;
        offA[m] = (row * 4 + ((gg + (row >> 1)) & 3)) * 8;
    }
    #pragma unroll
    for (int n = 0; n < 2; n++) {
        int row = wc * 32 + n * 16 + (lane & 15); int gg = lane >> 4;
        offB[n] = (row * 4 + ((gg + (row >> 1)) & 3)) * 8;
    }

    f32x4 acc[4][2];
    #pragma unroll
    for (int m = 0; m < 4; m++)
        #pragma unroll
        for (int n = 0; n < 2; n++) acc[m][n] = (f32x4){0.f, 0.f, 0.f, 0.f};

    int nk = Kc >> 5;
    for (int ks = 0; ks < nk; ks++) {
        gload16(pAh0, dA0);
        gload16(pAh1, dA1);
        if (NT == 3) { gload16(pAl0, dA0 + ALB); gload16(pAl1, dA1 + ALB); }
        gload16(pBh, dB);
        gload16(pBl, dB + 2048);
        pAh0 += 32; pAh1 += 32;
        if (NT == 3) { pAl0 += 32; pAl1 += 32; }
        pBh += 32; pBl += 32;
        __syncthreads();            // drains vmcnt(0): tiles ready
        bf16x8 ah[4], al[4], bh[2], bl[2];
        #pragma unroll
        for (int m = 0; m < 4; m++) {
            ah[m] = *(const bf16x8*)&lds[offA[m]];
            if (NT == 3) al[m] = *(const bf16x8*)&lds[ALB + offA[m]];
        }
        #pragma unroll
        for (int n = 0; n < 2; n++) {
            bh[n] = *(const bf16x8*)&lds[BHB + offB[n]];
            bl[n] = *(const bf16x8*)&lds[BLB + offB[n]];
        }
        #pragma unroll
        for (int m = 0; m < 4; m++)
            #pragma unroll
            for (int n = 0; n < 2; n++) {
                acc[m][n] = __builtin_amdgcn_mfma_f32_16x16x32_bf16(ah[m], bh[n], acc[m][n], 0, 0, 0);
                if (NT == 3)
                    acc[m][n] = __builtin_amdgcn_mfma_f32_16x16x32_bf16(al[m], bh[n], acc[m][n], 0, 0, 0);
                acc[m][n] = __builtin_amdgcn_mfma_f32_16x16x32_bf16(ah[m], bl[n], acc[m][n], 0, 0, 0);
            }
        __syncthreads();            // protect LDS before next overwrite
    }

    size_t pbase = (size_t)z * NN * Nc;       // partial-buffer slice (OUT=1)
    #pragma unroll
    for (int m = 0; m < 4; m++)
        #pragma unroll
        for (int n = 0; n < 2; n++) {
            int row = m0 + wr * 64 + m * 16 + (lane >> 4) * 4;
            int col = n0 + wc * 32 + n * 16 + (lane & 15);
            #pragma unroll
            for (int r = 0; r < 4; r++) {
                float v = acc[m][n][r];
                if (OUT == 0) Cb[(size_t)(row + r) * Nc + col] = f2bf(v);
                else          Cf[pbase + (size_t)(row + r) * Nc + col] = v;
            }
        }

    // fused s1/s2 epilogue (Wh path only; N-tile 64-aligned within one head)
    if (OUT == 0) {
        int head = (hs >= 0) ? (n0 >> hs) : 0;
        const float* ab = avec + head * 2 * aoff;
        float av1[2], av2[2];
        int colbase = n0 + wc * 32 + (lane & 15);
        #pragma unroll
        for (int n = 0; n < 2; n++) {
            int c = colbase + n * 16;
            int dd = (hs >= 0) ? (c & (aoff - 1)) : c;
            av1[n] = ab[dd];
            av2[n] = ab[dd + aoff];
        }
        #pragma unroll
        for (int m = 0; m < 4; m++)
            #pragma unroll
            for (int r = 0; r < 4; r++) {
                float p1 = 0.f, p2 = 0.f;
                #pragma unroll
                for (int n = 0; n < 2; n++) {
                    float v = acc[m][n][r];
                    p1 += v * av1[n];
                    p2 += v * av2[n];
                }
                #pragma unroll
                for (int o = 1; o < 16; o <<= 1) {
                    p1 += __shfl_xor(p1, o);
                    p2 += __shfl_xor(p2, o);
                }
                if ((lane & 15) == 0) {
                    int row = m0 + wr * 64 + m * 16 + (lane >> 4) * 4 + r;
                    atomicAdd(&sg1[head * NN + row], p1);
                    atomicAdd(&sg2[head * NN + row], p2);
                }
            }
    }
}

// ------- split-K reducer: one wave per row; sum partials, write ho, compute t1/t2 -------
__global__ __launch_bounds__(64) void k_red(
    const float* __restrict__ part, float* __restrict__ ho,
    const float* __restrict__ ao, float* __restrict__ t1, float* __restrict__ t2,
    int fout, int sko)
{
    int row = blockIdx.x;
    int lane = threadIdx.x;
    int C4 = fout >> 2;
    const float4* p4 = (const float4*)part;
    size_t stride4 = (size_t)NN * C4;
    float d1 = 0.f, d2 = 0.f;
    for (int c = lane; c < C4; c += 64) {
        size_t o = (size_t)row * C4 + c;
        float4 s = p4[o];
        for (int zz = 1; zz < sko; zz++) {
            float4 v = p4[o + (size_t)zz * stride4];
            s.x += v.x; s.y += v.y; s.z += v.z; s.w += v.w;
        }
        ((float4*)ho)[o] = s;
        int cc = c * 4;
        d1 += s.x * ao[cc]        + s.y * ao[cc + 1]
            + s.z * ao[cc + 2]    + s.w * ao[cc + 3];
        d2 += s.x * ao[fout + cc]     + s.y * ao[fout + cc + 1]
            + s.z * ao[fout + cc + 2] + s.w * ao[fout + cc + 3];
    }
    #pragma unroll
    for (int o = 32; o; o >>= 1) { d1 += __shfl_xor(d1, o); d2 += __shfl_xor(d2, o); }
    if (lane == 0) { t1[row] = d1; t2[row] = d2; }
}

// ------------- BIG agg: HP heads per wave (HP = 512/hid), 4 waves/block -------------
// Wave handles node i for heads h0..h0+HP-1: ci/row-offset table shared, weights per
// head, gather issues D*HP = 8 independent loads per round (D = 8/HP). Softmax fused
// (hidden under memory). C8 = 64/HP cols/head, G = HP neighbor groups, all constexpr.
template<int HP>
__global__ __launch_bounds__(256) void k_aggb(
    const unsigned short* __restrict__ hh, const float* __restrict__ s1,
    const float* __restrict__ s2, const int* __restrict__ rp, const int* __restrict__ ci,
    unsigned short* __restrict__ outH, int hid, int HD)
{
    constexpr int NHG = NH / HP;               // head-groups
    constexpr int D   = (HP == 1) ? 8 : (HP == 2) ? 4 : 2;   // neighbor depth
    constexpr int C8  = 64 / HP;               // ushort8 cols per head slice
    constexpr int G   = HP;                    // neighbor groups

    __shared__ float    wls[4][HP][64];
    __shared__ unsigned cls[4][64];

    int tid = threadIdx.x, wid = tid >> 6, lane = tid & 63;
    int hg = blockIdx.x & (NHG - 1);
    int i  = (blockIdx.x / NHG) * 4 + wid;
    int h0 = hg * HP;

    int base = rp[i], deg = rp[i + 1] - base;
    float s1i[HP];
    #pragma unroll
    for (int p = 0; p < HP; p++) s1i[p] = s1[(h0 + p) * NN + i];

    int col = lane & (C8 - 1), grp = lane >> (6 - (HP == 1 ? 0 : HP == 2 ? 1 : 2));
    // grp = lane / C8:
    grp = lane / C8;

    const uint4* h4 = (const uint4*)hh;
    unsigned ld8 = (unsigned)HD >> 3;
    unsigned hoff8[HP];
    #pragma unroll
    for (int p = 0; p < HP; p++) hoff8[p] = ((unsigned)(h0 + p) * hid) >> 3;

    float m_run[HP], s_run[HP], acc[HP][8], q[HP][8];
    #pragma unroll
    for (int p = 0; p < HP; p++) {
        m_run[p] = -1e30f; s_run[p] = 0.f;
        #pragma unroll
        for (int e = 0; e < 8; e++) { acc[p][e] = 0.f; q[p][e] = 0.f; }
    }

    for (int k0 = 0; k0 < deg; k0 += 64) {
        int n = min(64, deg - k0);
        bool act = lane < n;
        int j = 0;
        if (act) { j = ci[base + k0 + lane]; cls[wid][lane] = (unsigned)j * ld8; }
        #pragma unroll
        for (int p = 0; p < HP; p++) {
            float e = act ? lrelu(s1i[p] + s2[(h0 + p) * NN + j]) : -1e30f;
            float bm = e;
            #pragma unroll
            for (int o = 32; o; o >>= 1) bm = fmaxf(bm, __shfl_xor(bm, o));
            float m2 = fmaxf(m_run[p], bm);
            float wv = act ? expf(e - m2) : 0.f;
            float bs = wv;
            #pragma unroll
            for (int o = 32; o; o >>= 1) bs += __shfl_xor(bs, o);
            float scale = expf(m_run[p] - m2);          // 0 on first chunk
            s_run[p] = s_run[p] * scale + bs;
            #pragma unroll
            for (int e2 = 0; e2 < 8; e2++) acc[p][e2] *= scale;
            m_run[p] = m2;
            wls[wid][p][lane] = wv;                     // wave-synchronous LDS
        }

        int k = grp;
        for (; k + (D - 1) * G < n; k += D * G) {
            #pragma unroll
            for (int dd = 0; dd < D; dd++) {
                int kk = k + dd * G;
                unsigned rbase = cls[wid][kk];
                #pragma unroll
                for (int p = 0; p < HP; p++) {
                    float w0 = wls[wid][p][kk];
                    uint4 u0 = h4[rbase + hoff8[p] + col];
                    if (dd & 1) { ACC8(q[p],   w0, u0); }
                    else        { ACC8(acc[p], w0, u0); }
                }
            }
        }
        for (; k < n; k += G) {
            unsigned rbase = cls[wid][k];
            #pragma unroll
            for (int p = 0; p < HP; p++) {
                float w0 = wls[wid][p][k];
                uint4 u0 = h4[rbase + hoff8[p] + col];
                ACC8(acc[p], w0, u0);
            }
        }
        #pragma unroll
        for (int p = 0; p < HP; p++)
            #pragma unroll
            for (int e2 = 0; e2 < 8; e2++) { acc[p][e2] += q[p][e2]; q[p][e2] = 0.f; }
    }

    // cross-group reduction via register shuffles (no-op for HP==1)
    #pragma unroll
    for (int m = 32; m >= 1; m >>= 1) {
        if (m >= C8) {
            #pragma unroll
            for (int p = 0; p < HP; p++)
                #pragma unroll
                for (int e2 = 0; e2 < 8; e2++) acc[p][e2] += __shfl_xor(acc[p][e2], m);
        }
    }

    if (grp == 0) {
        #pragma unroll
        for (int p = 0; p < HP; p++) {
            float inv = 1.f / s_run[p];
            unsigned short hb[8];
            #pragma unroll
            for (int e2 = 0; e2 < 8; e2++) hb[e2] = f2bf(elu(acc[p][e2] * inv));
            size_t ob = ((size_t)i * HD + (size_t)(h0 + p) * hid) >> 3;
            uint4 ph;
            ph.x = (unsigned)hb[0] | ((unsigned)hb[1] << 16);
            ph.y = (unsigned)hb[2] | ((unsigned)hb[3] << 16);
            ph.z = (unsigned)hb[4] | ((unsigned)hb[5] << 16);
            ph.w = (unsigned)hb[6] | ((unsigned)hb[7] << 16);
            ((uint4*)outH)[ob + col] = ph;
        }
    }
}

// ------------- SMALL agg: ONE WAVE per (node, slice), fp32 gather (round-12) -------------
__global__ __launch_bounds__(64) void k_aggs(
    const float* __restrict__ hsrc, const float* __restrict__ t1, const float* __restrict__ t2,
    const int* __restrict__ rp, const int* __restrict__ ci,
    float* __restrict__ outF, unsigned short* __restrict__ outH,
    int fout, int SCtot)
{
    __shared__ float    wls[64];
    __shared__ unsigned cls[64];

    int blk = blockIdx.x;
    int i   = blk / SCtot;
    int sc  = blk - i * SCtot;
    int lane = threadIdx.x;
    int base = rp[i], deg = rp[i + 1] - base;
    float s1i = t1[i];

    int C4tot = fout >> 2;
    int soff  = sc * 64;
    int C4s   = min(64, C4tot - soff);        // 64 or 32 (pow2)
    int c4sh  = 31 - __clz(C4s);
    int col = lane & (C4s - 1);
    int grp = lane >> c4sh;
    int G   = 64 >> c4sh;

    const float4* h4 = (const float4*)hsrc;
    unsigned ld4 = (unsigned)fout >> 2;

    float m_run = -1e30f, s_run = 0.f;
    float4 acc = make_float4(0.f, 0.f, 0.f, 0.f);

    for (int k0 = 0; k0 < deg; k0 += 64) {
        int n = min(64, deg - k0);
        float e = -1e30f;
        unsigned coff = 0;
        if (lane < n) {
            int j = ci[base + k0 + lane];
            e = lrelu(s1i + t2[j]);
            coff = (unsigned)j * ld4 + soff;
        }
        float bm = e;
        #pragma unroll
        for (int o = 32; o; o >>= 1) bm = fmaxf(bm, __shfl_xor(bm, o));
        float m2 = fmaxf(m_run, bm);
        float wv = (lane < n) ? expf(e - m2) : 0.f;
        float bs = wv;
        #pragma unroll
        for (int o = 32; o; o >>= 1) bs += __shfl_xor(bs, o);
        float scale = expf(m_run - m2);
        s_run = s_run * scale + bs;
        acc.x *= scale; acc.y *= scale; acc.z *= scale; acc.w *= scale;
        m_run = m2;
        wls[lane] = wv;
        cls[lane] = coff;

        float4 q = make_float4(0,0,0,0);
        int k = grp;
        for (; k + G < n; k += 2 * G) {
            float w0 = wls[k], w1 = wls[k + G];
            float4 h0 = h4[cls[k]     + col];
            float4 h1 = h4[cls[k + G] + col];
            acc.x += w0 * h0.x; acc.y += w0 * h0.y; acc.z += w0 * h0.z; acc.w += w0 * h0.w;
            q.x   += w1 * h1.x; q.y   += w1 * h1.y; q.z   += w1 * h1.z; q.w   += w1 * h1.w;
        }
        if (k < n) {
            float w0 = wls[k];
            float4 h0 = h4[cls[k] + col];
            acc.x += w0 * h0.x; acc.y += w0 * h0.y; acc.z += w0 * h0.z; acc.w += w0 * h0.w;
        }
        acc.x += q.x; acc.y += q.y; acc.z += q.z; acc.w += q.w;
    }

    #pragma unroll
    for (int o = 64; o > 1; o >>= 1) {
        if (o > C4s) {
            int m = o >> 1;
            acc.x += __shfl_xor(acc.x, m); acc.y += __shfl_xor(acc.y, m);
            acc.z += __shfl_xor(acc.z, m); acc.w += __shfl_xor(acc.w, m);
        }
    }

    if (grp == 0) {
        float inv = 1.f / s_run;
        float4 val;
        val.x = elu(acc.x * inv); val.y = elu(acc.y * inv);
        val.z = elu(acc.z * inv); val.w = elu(acc.w * inv);
        size_t o4 = (size_t)i * ld4 + soff + col;
        if (outF) ((float4*)outF)[o4] = val;
        ushort4 h;
        h.x = f2bf(val.x); h.y = f2bf(val.y);
        h.z = f2bf(val.z); h.w = f2bf(val.w);
        ((ushort4*)outH)[o4] = h;
    }
}

// ---------------- host driver ----------------
extern "C" void kernel_launch(void* const* d_in, const int* in_sizes, int n_in,
                              void* d_out, int out_size, void* d_ws, size_t ws_size,
                              hipStream_t stream)
{
    const float* x   = (const float*)d_in[0];
    const float* adj = (const float*)d_in[1];
    struct L { int fin, hid, fout; };
    const L dims[6] = {{256,128,128},{128,256,256},{256,512,384},
                       {384,512,256},{256,256,128},{128,128,256}};
    const int SKwo[6] = {16, 8, 8, 8, 16, 8};
    const int SB = 2 * NH * NN;              // per-layer s1/s2 floats

    char* ws = (char*)d_ws;
    size_t off = 0;
    auto alloc = [&](size_t bytes) -> void* {
        void* p = ws + off;
        off = (off + bytes + 255) & ~(size_t)255;
        return p;
    };
    int*   rp   = (int*)alloc((NN + 1) * sizeof(int));
    int*   deg  = (int*)alloc(NN * sizeof(int));
    int*   ci   = (int*)alloc((size_t)(1 << 20) * sizeof(int));
    unsigned short* hh  = (unsigned short*)alloc((size_t)NN * 4096 * 2);  // bf16 h
    unsigned short* ghi = (unsigned short*)alloc((size_t)NN * 4096 * 2);  // bf16 hcat
    unsigned short* xhi = (unsigned short*)alloc((size_t)NN * 512 * 2);
    unsigned short* xlo = (unsigned short*)alloc((size_t)NN * 512 * 2);
    float* sball  = (float*)alloc((size_t)6 * SB * sizeof(float));        // all-layer s1/s2
    float* hopart = (float*)alloc((size_t)NN * 3072 * sizeof(float));     // split-K partials
    float* ho     = (float*)alloc((size_t)NN * 384 * sizeof(float));      // reduced ho (fp32)
    float* t12    = (float*)alloc((size_t)2 * NN * sizeof(float));        // t1/t2

    unsigned short* whh[6]; unsigned short* whl[6];
    unsigned short* woh[6]; unsigned short* wol[6];
    TSDesc td;
    int nblk = 0;
    for (int l = 0; l < 6; l++) {
        int fin = dims[l].fin, hid = dims[l].hid, fout = dims[l].fout;
        int HD = NH * hid;
        size_t szWh = (size_t)fin * HD, szWo = (size_t)HD * fout;
        whh[l] = (unsigned short*)alloc(szWh * 2);
        whl[l] = (unsigned short*)alloc(szWh * 2);
        woh[l] = (unsigned short*)alloc(szWo * 2);
        wol[l] = (unsigned short*)alloc(szWo * 2);
        int hs = (hid == 128) ? 7 : (hid == 256) ? 8 : 9;
        td.B[2*l] = (const float*)d_in[2 + l * 4 + 0];
        td.bh[2*l] = whh[l]; td.bl[2*l] = whl[l];
        td.K[2*l] = fin; td.Nc[2*l] = HD; td.hs[2*l] = hs;
        td.start[2*l] = nblk; nblk += (fin / 64) * (HD / 64);
        td.B[2*l+1] = (const float*)d_in[2 + l * 4 + 2];
        td.bh[2*l+1] = woh[l]; td.bl[2*l+1] = wol[l];
        td.K[2*l+1] = HD; td.Nc[2*l+1] = fout; td.hs[2*l+1] = -1;
        td.start[2*l+1] = nblk; nblk += (HD / 64) * (fout / 64);
    }
    td.start[12] = nblk;

    // ---- front matter: one memset (s1/s2 only) + CSR + x split + weight splits ----
    hipMemsetAsync(sball, 0, (size_t)6 * SB * sizeof(float), stream);
    k_count<<<NN / 4, 256, 0, stream>>>(adj, deg);
    k_scan <<<1, 1024, 0, stream>>>(deg, rp);
    k_fill <<<NN / 4, 256, 0, stream>>>(adj, rp, ci);
    k_split<<<(NN * 256 / 4 + 255) / 256, 256, 0, stream>>>(x, xhi, xlo, NN * 256 / 4);
    k_tsplit_all<<<nblk, 256, 0, stream>>>(td);

    for (int l = 0; l < 6; l++) {
        int fin = dims[l].fin, hid = dims[l].hid, fout = dims[l].fout;
        int HD = NH * hid;
        int hs = (hid == 128) ? 7 : (hid == 256) ? 8 : 9;
        const float* ah = (const float*)d_in[2 + l * 4 + 1];
        const float* ao = (const float*)d_in[2 + l * 4 + 3];

        float* s1 = sball + (size_t)l * SB;
        float* s2 = s1 + NH * NN;
        float* t1 = t12;
        float* t2 = t12 + NN;

        // --- h = x @ Wh  (bf16 out + fused s1/s2), y<->XCD colocate, 64-wide tiles ---
        int nx1 = HD / 64;
        if (l == 0)
            k_mfma<0,3><<<nx1 * 16, 256, 0, stream>>>(xhi, xlo, whh[l], whl[l], nullptr, hh, HD,
                                                      fin, fin, ah, s1, s2, hs, hid, nx1, 1, 0);
        else
            k_mfma<0,2><<<nx1 * 16, 256, 0, stream>>>(xhi, nullptr, whh[l], whl[l], nullptr, hh, HD,
                                                      fin, fin, ah, s1, s2, hs, hid, nx1, 1, 0);

        // per-head masked softmax aggregation: HP heads per wave, 4 waves/block
        if (hid == 512)
            k_aggb<1><<<(NN / 4) * 8, 256, 0, stream>>>(hh, s1, s2, rp, ci, ghi, hid, HD);
        else if (hid == 256)
            k_aggb<2><<<(NN / 4) * 4, 256, 0, stream>>>(hh, s1, s2, rp, ci, ghi, hid, HD);
        else
            k_aggb<4><<<(NN / 4) * 2, 256, 0, stream>>>(hh, s1, s2, rp, ci, ghi, hid, HD);

        // --- ho = hcat @ Wo  (split-K partial stores, NO atomics), z<->XCD colocate ---
        int sko = SKwo[l];
        int nx2 = fout / 64;
        k_mfma<1,2><<<nx2 * 16 * sko, 256, 0, stream>>>(ghi, nullptr, woh[l], wol[l], hopart,
                                                        nullptr, fout, HD, HD / sko,
                                                        nullptr, nullptr, nullptr, -1, fout,
                                                        nx2, sko, 1);

        // reduce partials -> ho (fp32) + t1/t2 (plain stores, deterministic)
        k_red<<<NN, 64, 0, stream>>>(hopart, ho, ao, t1, t2, fout, sko);

        float* outF = (l == 5) ? (float*)d_out : nullptr;
        int SCtot = (fout / 4 + 63) / 64;      // 1,1,2,1,1,1
        k_aggs<<<NN * SCtot, 64, 0, stream>>>(ho, t1, t2, rp, ci, outF, xhi, fout, SCtot);
    }
}

// Round 18
// 433.298 us; speedup vs baseline: 1.2964x; 1.1192x over previous
//
#include <hip/hip_runtime.h>
#include <hip/hip_bf16.h>
#include <math.h>

#define NN 2048          // n_nodes
#define NH 8             // heads
#define LRALPHA 0.2f

typedef short bf16x8 __attribute__((ext_vector_type(8)));
typedef float f32x4  __attribute__((ext_vector_type(4)));

static __device__ __forceinline__ float lrelu(float x){ return x > 0.f ? x : LRALPHA * x; }
static __device__ __forceinline__ float elu(float x){ return x > 0.f ? x : expm1f(x); }

static __device__ __forceinline__ unsigned short f2bf(float v){
    unsigned u = __float_as_uint(v);
    unsigned r = (u + 0x7fffu + ((u >> 16) & 1u)) >> 16;
    return (unsigned short)r;
}
static __device__ __forceinline__ float bf2f(unsigned short b){
    return __uint_as_float(((unsigned)b) << 16);
}
static __device__ __forceinline__ float blo(unsigned u){ return __uint_as_float(u << 16); }
static __device__ __forceinline__ float bhi(unsigned u){ return __uint_as_float(u & 0xffff0000u); }

static __device__ __forceinline__ void gload16(const void* g, void* l){
    __builtin_amdgcn_global_load_lds((const __attribute__((address_space(1))) void*)g,
                                     (__attribute__((address_space(3))) void*)l, 16, 0, 0);
}

// accumulate 8 bf16 elems of uint4 u into float A[8] weighted by wv
#define ACC8(A, wv, u) \
    A[0] += wv * blo(u.x); A[1] += wv * bhi(u.x); \
    A[2] += wv * blo(u.y); A[3] += wv * bhi(u.y); \
    A[4] += wv * blo(u.z); A[5] += wv * bhi(u.z); \
    A[6] += wv * blo(u.w); A[7] += wv * bhi(u.w);

// ---------------- CSR build (deterministic, sorted by column) ----------------
__global__ void k_count(const float* __restrict__ adj, int* __restrict__ deg) {
    int gw   = (blockIdx.x * blockDim.x + threadIdx.x) >> 6;
    int lane = threadIdx.x & 63;
    if (gw >= NN) return;
    const float* row = adj + (size_t)gw * NN;
    int cnt = 0;
    for (int j = lane; j < NN; j += 64) cnt += (row[j] > 0.f) ? 1 : 0;
    #pragma unroll
    for (int off = 32; off; off >>= 1) cnt += __shfl_down(cnt, off);
    if (lane == 0) deg[gw] = cnt;
}

__global__ void k_scan(const int* __restrict__ deg, int* __restrict__ rp) {
    __shared__ int a[NN], b[NN];
    int t = threadIdx.x;                       // 1024 threads
    for (int i = t; i < NN; i += 1024) a[i] = deg[i];
    __syncthreads();
    int* src = a; int* dst = b;
    for (int off = 1; off < NN; off <<= 1) {
        for (int i = t; i < NN; i += 1024)
            dst[i] = src[i] + (i >= off ? src[i - off] : 0);
        __syncthreads();
        int* tmp = src; src = dst; dst = tmp;
    }
    for (int i = t; i < NN; i += 1024) rp[i + 1] = src[i];
    if (t == 0) rp[0] = 0;
}

__global__ void k_fill(const float* __restrict__ adj, const int* __restrict__ rp,
                       int* __restrict__ ci) {
    int gw   = (blockIdx.x * blockDim.x + threadIdx.x) >> 6;
    int lane = threadIdx.x & 63;
    if (gw >= NN) return;
    const float* row = adj + (size_t)gw * NN;
    int base = rp[gw];
    for (int j0 = 0; j0 < NN; j0 += 64) {
        bool v = row[j0 + lane] > 0.f;
        unsigned long long m = __ballot(v);
        int pos = __popcll(m & ((1ULL << lane) - 1ULL));
        if (v) ci[base + pos] = j0 + lane;
        base += __popcll(m);
    }
}

// ---------------- split fp32 -> bf16 hi/lo (input x only) ----------------
__global__ void k_split(const float* __restrict__ src, unsigned short* __restrict__ hi,
                        unsigned short* __restrict__ lo, int n4) {
    int i = blockIdx.x * 256 + threadIdx.x;
    if (i >= n4) return;
    float4 v = ((const float4*)src)[i];
    ushort4 h, l;
    h.x = f2bf(v.x); l.x = f2bf(v.x - bf2f(h.x));
    h.y = f2bf(v.y); l.y = f2bf(v.y - bf2f(h.y));
    h.z = f2bf(v.z); l.z = f2bf(v.z - bf2f(h.z));
    h.w = f2bf(v.w); l.w = f2bf(v.w - bf2f(h.w));
    ((ushort4*)hi)[i] = h;
    ((ushort4*)lo)[i] = l;
}

// ------- ALL weight transposes+splits in ONE launch ----
struct TSDesc {
    const float* B[12];
    unsigned short* bh[12];
    unsigned short* bl[12];
    int K[12], Nc[12], hs[12];
    int start[13];
};

__global__ __launch_bounds__(256) void k_tsplit_all(TSDesc d) {
    __shared__ float t[64][65];
    int b = blockIdx.x;
    int s = 0;
    while (b >= d.start[s + 1]) s++;
    int lb = b - d.start[s];
    int K = d.K[s], Nc = d.Nc[s], hs = d.hs[s];
    int tilesX = K >> 6;
    int kb = (lb % tilesX) * 64, cb = (lb / tilesX) * 64;
    const float* B = d.B[s];
    unsigned short* bth = d.bh[s];
    unsigned short* btl = d.bl[s];

    int tid = threadIdx.x;
    #pragma unroll
    for (int i = 0; i < 16; i++) {
        int idx = i * 256 + tid;
        int kk = idx >> 6, cc = idx & 63;
        int c = cb + cc, k = kb + kk;
        float v;
        if (hs < 0) v = B[(size_t)k * Nc + c];
        else {
            int hid = 1 << hs; int head = c >> hs; int dd = c & (hid - 1);
            v = B[((size_t)head * K + k) * hid + dd];
        }
        t[kk][cc] = v;
    }
    __syncthreads();
    #pragma unroll
    for (int i = 0; i < 16; i++) {
        int idx = i * 256 + tid;
        int cc = idx >> 6, kk = idx & 63;
        float v = t[kk][cc];
        unsigned short h = f2bf(v);
        size_t o = (size_t)(cb + cc) * K + kb + kk;
        bth[o] = h;
        btl[o] = f2bf(v - bf2f(h));
    }
}

// ---------- split-bf16 MFMA GEMM, 256 threads, 128(M) x 64(N) tile ----------
// Both OUT modes store bf16 to Cb at pbase + row*Nc + col (pbase = z*NN*Nc; z=0 if !zcol).
// OUT=0 additionally runs the fused s1/s2 epilogue.
template<int OUT, int NT>
__global__ __launch_bounds__(256) void k_mfma(
    const unsigned short* __restrict__ Ah, const unsigned short* __restrict__ Al,
    const unsigned short* __restrict__ Bh, const unsigned short* __restrict__ Bl,
    unsigned short* __restrict__ Cb, int Nc, int K, int Kc,
    const float* __restrict__ avec, float* __restrict__ sg1, float* __restrict__ sg2,
    int hs, int aoff, int nx, int nz, int zcol)
{
    constexpr int ALB = 4096;                       // ushort units (NT=3 only)
    constexpr int BHB = (NT == 3) ? 8192 : 4096;
    constexpr int BLB = BHB + 2048;
    __shared__ unsigned short lds[(NT == 3) ? 12288 : 8192];  // 24KB / 16KB
    int tid = threadIdx.x, lane = tid & 63, w = tid >> 6;

    int g = blockIdx.x;
    int xcd = g & 7, q = g >> 3;
    int x, y, z;
    if (zcol) {
        int zper = nz >> 3;
        z = xcd + 8 * (q % zper);
        int r = q / zper;
        int nxy = nx * 16;
        int r2 = r + xcd * (nxy >> 3); if (r2 >= nxy) r2 -= nxy;
        x = r2 % nx; y = r2 / nx;
    } else {
        y = xcd + 8 * (q & 1);
        x = q >> 1; z = 0;
    }
    int m0 = y * 128, n0 = x * 64;
    int kbeg = z * Kc;

    int ra0 = tid >> 2;       int ga0 = ((tid & 3) - (ra0 >> 1)) & 3;
    int ra1 = 64 + (tid >> 2); int ga1 = ((tid & 3) - (ra1 >> 1)) & 3;
    int rb  = tid >> 2;       int gb  = ((tid & 3) - (rb >> 1)) & 3;
    const unsigned short* pAh0 = Ah + (size_t)(m0 + ra0) * K + kbeg + ga0 * 8;
    const unsigned short* pAh1 = Ah + (size_t)(m0 + ra1) * K + kbeg + ga1 * 8;
    const unsigned short* pAl0 = (NT == 3) ? Al + (size_t)(m0 + ra0) * K + kbeg + ga0 * 8 : nullptr;
    const unsigned short* pAl1 = (NT == 3) ? Al + (size_t)(m0 + ra1) * K + kbeg + ga1 * 8 : nullptr;
    const unsigned short* pBh  = Bh + (size_t)(n0 + rb) * K + kbeg + gb * 8;
    const unsigned short* pBl  = Bl + (size_t)(n0 + rb) * K + kbeg + gb * 8;
    unsigned short* dA0 = &lds[w * 512];
    unsigned short* dA1 = &lds[2048 + w * 512];
    unsigned short* dB  = &lds[BHB + w * 512];

    int wr = w >> 1, wc = w & 1;
    int offA[4], offB[2];
    #pragma unroll
    for (int m = 0; m < 4; m++) {
        int row = wr * 64 + m * 16 + (lane & 15); int gg = lane >> 4;
        offA[m] = (row * 4 + ((gg + (row >> 1)) & 3)) * 8;
    }
    #pragma unroll
    for (int n = 0; n < 2; n++) {
        int row = wc * 32 + n * 16 + (lane & 15); int gg = lane >> 4;
        offB[n] = (row * 4 + ((gg + (row >> 1)) & 3)) * 8;
    }

    f32x4 acc[4][2];
    #pragma unroll
    for (int m = 0; m < 4; m++)
        #pragma unroll
        for (int n = 0; n < 2; n++) acc[m][n] = (f32x4){0.f, 0.f, 0.f, 0.f};

    int nk = Kc >> 5;
    for (int ks = 0; ks < nk; ks++) {
        gload16(pAh0, dA0);
        gload16(pAh1, dA1);
        if (NT == 3) { gload16(pAl0, dA0 + ALB); gload16(pAl1, dA1 + ALB); }
        gload16(pBh, dB);
        gload16(pBl, dB + 2048);
        pAh0 += 32; pAh1 += 32;
        if (NT == 3) { pAl0 += 32; pAl1 += 32; }
        pBh += 32; pBl += 32;
        __syncthreads();            // drains vmcnt(0): tiles ready
        bf16x8 ah[4], al[4], bh[2], bl[2];
        #pragma unroll
        for (int m = 0; m < 4; m++) {
            ah[m] = *(const bf16x8*)&lds[offA[m]];
            if (NT == 3) al[m] = *(const bf16x8*)&lds[ALB + offA[m]];
        }
        #pragma unroll
        for (int n = 0; n < 2; n++) {
            bh[n] = *(const bf16x8*)&lds[BHB + offB[n]];
            bl[n] = *(const bf16x8*)&lds[BLB + offB[n]];
        }
        #pragma unroll
        for (int m = 0; m < 4; m++)
            #pragma unroll
            for (int n = 0; n < 2; n++) {
                acc[m][n] = __builtin_amdgcn_mfma_f32_16x16x32_bf16(ah[m], bh[n], acc[m][n], 0, 0, 0);
                if (NT == 3)
                    acc[m][n] = __builtin_amdgcn_mfma_f32_16x16x32_bf16(al[m], bh[n], acc[m][n], 0, 0, 0);
                acc[m][n] = __builtin_amdgcn_mfma_f32_16x16x32_bf16(ah[m], bl[n], acc[m][n], 0, 0, 0);
            }
        __syncthreads();            // protect LDS before next overwrite
    }

    size_t pbase = (size_t)z * NN * Nc;       // partial slice (z=0 when !zcol)
    #pragma unroll
    for (int m = 0; m < 4; m++)
        #pragma unroll
        for (int n = 0; n < 2; n++) {
            int row = m0 + wr * 64 + m * 16 + (lane >> 4) * 4;
            int col = n0 + wc * 32 + n * 16 + (lane & 15);
            #pragma unroll
            for (int r = 0; r < 4; r++)
                Cb[pbase + (size_t)(row + r) * Nc + col] = f2bf(acc[m][n][r]);
        }

    // fused s1/s2 epilogue (Wh path only; N-tile 64-aligned within one head)
    if (OUT == 0) {
        int head = (hs >= 0) ? (n0 >> hs) : 0;
        const float* ab = avec + head * 2 * aoff;
        float av1[2], av2[2];
        int colbase = n0 + wc * 32 + (lane & 15);
        #pragma unroll
        for (int n = 0; n < 2; n++) {
            int c = colbase + n * 16;
            int dd = (hs >= 0) ? (c & (aoff - 1)) : c;
            av1[n] = ab[dd];
            av2[n] = ab[dd + aoff];
        }
        #pragma unroll
        for (int m = 0; m < 4; m++)
            #pragma unroll
            for (int r = 0; r < 4; r++) {
                float p1 = 0.f, p2 = 0.f;
                #pragma unroll
                for (int n = 0; n < 2; n++) {
                    float v = acc[m][n][r];
                    p1 += v * av1[n];
                    p2 += v * av2[n];
                }
                #pragma unroll
                for (int o = 1; o < 16; o <<= 1) {
                    p1 += __shfl_xor(p1, o);
                    p2 += __shfl_xor(p2, o);
                }
                if ((lane & 15) == 0) {
                    int row = m0 + wr * 64 + m * 16 + (lane >> 4) * 4 + r;
                    atomicAdd(&sg1[head * NN + row], p1);
                    atomicAdd(&sg2[head * NN + row], p2);
                }
            }
    }
}

// ------- split-K reducer: 4 waves/block, one row per wave, bf16 partials -------
// Sums sko bf16 partial slices in fp32, writes ho (bf16) + t1/t2 (fp32 dots).
__global__ __launch_bounds__(256) void k_red(
    const unsigned short* __restrict__ part, unsigned short* __restrict__ ho,
    const float* __restrict__ ao, float* __restrict__ t1, float* __restrict__ t2,
    int fout, int sko)
{
    int wid = threadIdx.x >> 6;
    int lane = threadIdx.x & 63;
    int row = blockIdx.x * 4 + wid;
    int C8 = fout >> 3;                 // uint4 cols (16/32/48), <= 48 < 64
    const uint4* p8 = (const uint4*)part;
    size_t stride8 = (size_t)NN * C8;
    float d1 = 0.f, d2 = 0.f;
    if (lane < C8) {
        size_t o = (size_t)row * C8 + lane;
        float s[8];
        #pragma unroll
        for (int e = 0; e < 8; e++) s[e] = 0.f;
        for (int zz = 0; zz < sko; zz++) {
            uint4 u = p8[o + (size_t)zz * stride8];
            ACC8(s, 1.f, u);
        }
        unsigned short hb[8];
        #pragma unroll
        for (int e = 0; e < 8; e++) hb[e] = f2bf(s[e]);
        uint4 ph;
        ph.x = (unsigned)hb[0] | ((unsigned)hb[1] << 16);
        ph.y = (unsigned)hb[2] | ((unsigned)hb[3] << 16);
        ph.z = (unsigned)hb[4] | ((unsigned)hb[5] << 16);
        ph.w = (unsigned)hb[6] | ((unsigned)hb[7] << 16);
        ((uint4*)ho)[o] = ph;
        int cc = lane * 8;
        #pragma unroll
        for (int e = 0; e < 8; e++) {
            d1 += s[e] * ao[cc + e];
            d2 += s[e] * ao[fout + cc + e];
        }
    }
    #pragma unroll
    for (int o = 32; o; o >>= 1) { d1 += __shfl_xor(d1, o); d2 += __shfl_xor(d2, o); }
    if (lane == 0) { t1[row] = d1; t2[row] = d2; }
}

// ------------- BIG agg: 4 waves/block, one (node,head) per wave, barrier-free -------------
__global__ __launch_bounds__(256) void k_aggb(
    const unsigned short* __restrict__ hh, const float* __restrict__ s1,
    const float* __restrict__ s2, const int* __restrict__ rp, const int* __restrict__ ci,
    unsigned short* __restrict__ outH, int hid, int HD, int c8sh)
{
    __shared__ float    wls[256];
    __shared__ unsigned cls[256];

    int tid = threadIdx.x;
    int wid = tid >> 6;
    int lane = tid & 63;
    int head = blockIdx.x & (NH - 1);
    int i    = (blockIdx.x >> 3) * 4 + wid;
    float* wlsw = wls + wid * 64;
    unsigned* clsw = cls + wid * 64;

    int base = rp[i], deg = rp[i + 1] - base;
    float s1i = s1[head * NN + i];
    const float* s2h = s2 + head * NN;

    int C8  = 1 << c8sh;                  // ushort8 cols per head slice (16/32/64)
    int G   = 64 >> c8sh;                 // neighbor groups (4/2/1)
    int col = lane & (C8 - 1);
    int grp = lane >> c8sh;

    const uint4* h4 = (const uint4*)hh;
    unsigned hoff8 = (unsigned)(head * hid) >> 3;
    unsigned ld8   = (unsigned)HD >> 3;

    float m_run = -1e30f, s_run = 0.f;
    float aA[8], qB[8];
    #pragma unroll
    for (int e = 0; e < 8; e++) { aA[e] = 0.f; qB[e] = 0.f; }

    for (int k0 = 0; k0 < deg; k0 += 64) {
        int n = min(64, deg - k0);
        float e = -1e30f;
        unsigned coff = 0;
        if (lane < n) {
            int j = ci[base + k0 + lane];
            e = lrelu(s1i + s2h[j]);
            coff = (unsigned)j * ld8 + hoff8;
        }
        float bm = e;
        #pragma unroll
        for (int o = 32; o; o >>= 1) bm = fmaxf(bm, __shfl_xor(bm, o));
        float m2 = fmaxf(m_run, bm);
        float wv = (lane < n) ? expf(e - m2) : 0.f;
        float bs = wv;
        #pragma unroll
        for (int o = 32; o; o >>= 1) bs += __shfl_xor(bs, o);
        float scale = expf(m_run - m2);          // 0 on first chunk
        s_run = s_run * scale + bs;
        #pragma unroll
        for (int e2 = 0; e2 < 8; e2++) aA[e2] *= scale;
        m_run = m2;
        wlsw[lane] = wv;
        clsw[lane] = coff;                       // wave-synchronous LDS (no barrier)

        int k = grp;
        for (; k + G < n; k += 2 * G) {
            float w0 = wlsw[k], w1 = wlsw[k + G];
            uint4 u0 = h4[clsw[k]     + col];
            uint4 u1 = h4[clsw[k + G] + col];
            ACC8(aA, w0, u0);
            ACC8(qB, w1, u1);
        }
        if (k < n) {
            float w0 = wlsw[k];
            uint4 u0 = h4[clsw[k] + col];
            ACC8(aA, w0, u0);
        }
    }
    #pragma unroll
    for (int e2 = 0; e2 < 8; e2++) aA[e2] += qB[e2];

    // cross-group reduction via register shuffles (G=1: none)
    #pragma unroll
    for (int m = 32; m >= 1; m >>= 1) {
        if (m >= C8) {
            #pragma unroll
            for (int e2 = 0; e2 < 8; e2++) aA[e2] += __shfl_xor(aA[e2], m);
        }
    }

    if (grp == 0) {
        float inv = 1.f / s_run;
        unsigned short hb[8];
        #pragma unroll
        for (int e2 = 0; e2 < 8; e2++) hb[e2] = f2bf(elu(aA[e2] * inv));
        size_t ob = ((size_t)i * HD + head * hid) >> 3;
        uint4 ph;
        ph.x = (unsigned)hb[0] | ((unsigned)hb[1] << 16);
        ph.y = (unsigned)hb[2] | ((unsigned)hb[3] << 16);
        ph.z = (unsigned)hb[4] | ((unsigned)hb[5] << 16);
        ph.w = (unsigned)hb[6] | ((unsigned)hb[7] << 16);
        ((uint4*)outH)[ob + col] = ph;
    }
}

// ------------- SMALL agg: 4 waves/block, one node per wave, bf16 gather -------------
// fout<=384 -> C8s = fout/8 uint4 cols (16/32/48) fits one wave; 48-case uses G=1.
__global__ __launch_bounds__(256) void k_aggs(
    const unsigned short* __restrict__ ho, const float* __restrict__ t1,
    const float* __restrict__ t2, const int* __restrict__ rp, const int* __restrict__ ci,
    float* __restrict__ outF, unsigned short* __restrict__ outH, int fout)
{
    __shared__ float    wls[256];
    __shared__ unsigned cls[256];

    int tid = threadIdx.x;
    int wid = tid >> 6;
    int lane = tid & 63;
    int i = blockIdx.x * 4 + wid;
    float* wlsw = wls + wid * 64;
    unsigned* clsw = cls + wid * 64;

    int base = rp[i], deg = rp[i + 1] - base;
    float s1i = t1[i];

    int C8s = fout >> 3;                 // 16 / 32 / 48
    int G, col, grp; bool act;
    if (C8s == 48) { G = 1; col = lane; grp = 0; act = lane < 48; }
    else {
        int sh = 31 - __clz(C8s);
        G = 64 >> sh; col = lane & (C8s - 1); grp = lane >> sh; act = true;
    }

    const uint4* h4 = (const uint4*)ho;
    unsigned ld8 = (unsigned)fout >> 3;

    float m_run = -1e30f, s_run = 0.f;
    float aA[8], qB[8];
    #pragma unroll
    for (int e = 0; e < 8; e++) { aA[e] = 0.f; qB[e] = 0.f; }

    for (int k0 = 0; k0 < deg; k0 += 64) {
        int n = min(64, deg - k0);
        float e = -1e30f;
        unsigned coff = 0;
        if (lane < n) {
            int j = ci[base + k0 + lane];
            e = lrelu(s1i + t2[j]);
            coff = (unsigned)j * ld8;
        }
        float bm = e;
        #pragma unroll
        for (int o = 32; o; o >>= 1) bm = fmaxf(bm, __shfl_xor(bm, o));
        float m2 = fmaxf(m_run, bm);
        float wv = (lane < n) ? expf(e - m2) : 0.f;
        float bs = wv;
        #pragma unroll
        for (int o = 32; o; o >>= 1) bs += __shfl_xor(bs, o);
        float scale = expf(m_run - m2);
        s_run = s_run * scale + bs;
        #pragma unroll
        for (int e2 = 0; e2 < 8; e2++) aA[e2] *= scale;
        m_run = m2;
        wlsw[lane] = wv;
        clsw[lane] = coff;

        if (act) {
            int k = grp;
            for (; k + G < n; k += 2 * G) {
                float w0 = wlsw[k], w1 = wlsw[k + G];
                uint4 u0 = h4[clsw[k]     + col];
                uint4 u1 = h4[clsw[k + G] + col];
                ACC8(aA, w0, u0);
                ACC8(qB, w1, u1);
            }
            if (k < n) {
                float w0 = wlsw[k];
                uint4 u0 = h4[clsw[k] + col];
                ACC8(aA, w0, u0);
            }
        }
    }
    #pragma unroll
    for (int e2 = 0; e2 < 8; e2++) aA[e2] += qB[e2];

    // cross-group reduction (pow2 cases only; C8s=48 has G=1)
    #pragma unroll
    for (int m = 32; m >= 1; m >>= 1) {
        if (m >= C8s) {
            #pragma unroll
            for (int e2 = 0; e2 < 8; e2++) aA[e2] += __shfl_xor(aA[e2], m);
        }
    }

    if (grp == 0 && act) {
        float inv = 1.f / s_run;
        float v[8];
        #pragma unroll
        for (int e2 = 0; e2 < 8; e2++) v[e2] = elu(aA[e2] * inv);
        size_t ob = (size_t)i * C8s + col;         // uint4 units
        if (outF) {
            size_t o4 = ob * 2;                    // float4 units
            ((float4*)outF)[o4]     = make_float4(v[0], v[1], v[2], v[3]);
            ((float4*)outF)[o4 + 1] = make_float4(v[4], v[5], v[6], v[7]);
        }
        unsigned short hb[8];
        #pragma unroll
        for (int e2 = 0; e2 < 8; e2++) hb[e2] = f2bf(v[e2]);
        uint4 ph;
        ph.x = (unsigned)hb[0] | ((unsigned)hb[1] << 16);
        ph.y = (unsigned)hb[2] | ((unsigned)hb[3] << 16);
        ph.z = (unsigned)hb[4] | ((unsigned)hb[5] << 16);
        ph.w = (unsigned)hb[6] | ((unsigned)hb[7] << 16);
        ((uint4*)outH)[ob] = ph;
    }
}

// ---------------- host driver ----------------
extern "C" void kernel_launch(void* const* d_in, const int* in_sizes, int n_in,
                              void* d_out, int out_size, void* d_ws, size_t ws_size,
                              hipStream_t stream)
{
    const float* x   = (const float*)d_in[0];
    const float* adj = (const float*)d_in[1];
    struct L { int fin, hid, fout; };
    const L dims[6] = {{256,128,128},{128,256,256},{256,512,384},
                       {384,512,256},{256,256,128},{128,128,256}};
    const int SKO = 8;                       // split-K for all Wo GEMMs
    const int SB = 2 * NH * NN;              // per-layer s1/s2 floats

    char* ws = (char*)d_ws;
    size_t off = 0;
    auto alloc = [&](size_t bytes) -> void* {
        void* p = ws + off;
        off = (off + bytes + 255) & ~(size_t)255;
        return p;
    };
    int*   rp   = (int*)alloc((NN + 1) * sizeof(int));
    int*   deg  = (int*)alloc(NN * sizeof(int));
    int*   ci   = (int*)alloc((size_t)(1 << 20) * sizeof(int));
    unsigned short* hh  = (unsigned short*)alloc((size_t)NN * 4096 * 2);  // bf16 h
    unsigned short* ghi = (unsigned short*)alloc((size_t)NN * 4096 * 2);  // bf16 hcat
    unsigned short* xhi = (unsigned short*)alloc((size_t)NN * 512 * 2);
    unsigned short* xlo = (unsigned short*)alloc((size_t)NN * 512 * 2);
    float* sball  = (float*)alloc((size_t)6 * SB * sizeof(float));        // all-layer s1/s2
    unsigned short* hopart = (unsigned short*)alloc((size_t)NN * 3072 * 2); // bf16 partials
    unsigned short* ho     = (unsigned short*)alloc((size_t)NN * 384 * 2);  // bf16 ho
    float* t12    = (float*)alloc((size_t)2 * NN * sizeof(float));        // t1/t2

    unsigned short* whh[6]; unsigned short* whl[6];
    unsigned short* woh[6]; unsigned short* wol[6];
    TSDesc td;
    int nblk = 0;
    for (int l = 0; l < 6; l++) {
        int fin = dims[l].fin, hid = dims[l].hid, fout = dims[l].fout;
        int HD = NH * hid;
        size_t szWh = (size_t)fin * HD, szWo = (size_t)HD * fout;
        whh[l] = (unsigned short*)alloc(szWh * 2);
        whl[l] = (unsigned short*)alloc(szWh * 2);
        woh[l] = (unsigned short*)alloc(szWo * 2);
        wol[l] = (unsigned short*)alloc(szWo * 2);
        int hs = (hid == 128) ? 7 : (hid == 256) ? 8 : 9;
        td.B[2*l] = (const float*)d_in[2 + l * 4 + 0];
        td.bh[2*l] = whh[l]; td.bl[2*l] = whl[l];
        td.K[2*l] = fin; td.Nc[2*l] = HD; td.hs[2*l] = hs;
        td.start[2*l] = nblk; nblk += (fin / 64) * (HD / 64);
        td.B[2*l+1] = (const float*)d_in[2 + l * 4 + 2];
        td.bh[2*l+1] = woh[l]; td.bl[2*l+1] = wol[l];
        td.K[2*l+1] = HD; td.Nc[2*l+1] = fout; td.hs[2*l+1] = -1;
        td.start[2*l+1] = nblk; nblk += (HD / 64) * (fout / 64);
    }
    td.start[12] = nblk;

    // ---- front matter: one memset (s1/s2 only) + CSR + x split + weight splits ----
    hipMemsetAsync(sball, 0, (size_t)6 * SB * sizeof(float), stream);
    k_count<<<NN / 4, 256, 0, stream>>>(adj, deg);
    k_scan <<<1, 1024, 0, stream>>>(deg, rp);
    k_fill <<<NN / 4, 256, 0, stream>>>(adj, rp, ci);
    k_split<<<(NN * 256 / 4 + 255) / 256, 256, 0, stream>>>(x, xhi, xlo, NN * 256 / 4);
    k_tsplit_all<<<nblk, 256, 0, stream>>>(td);

    for (int l = 0; l < 6; l++) {
        int fin = dims[l].fin, hid = dims[l].hid, fout = dims[l].fout;
        int HD = NH * hid;
        int hs = (hid == 128) ? 7 : (hid == 256) ? 8 : 9;
        int c8sh = hs - 3;                     // log2(hid/8)
        const float* ah = (const float*)d_in[2 + l * 4 + 1];
        const float* ao = (const float*)d_in[2 + l * 4 + 3];

        float* s1 = sball + (size_t)l * SB;
        float* s2 = s1 + NH * NN;
        float* t1 = t12;
        float* t2 = t12 + NN;

        // --- h = x @ Wh  (bf16 out + fused s1/s2), y<->XCD colocate, 64-wide tiles ---
        int nx1 = HD / 64;
        if (l == 0)
            k_mfma<0,3><<<nx1 * 16, 256, 0, stream>>>(xhi, xlo, whh[l], whl[l], hh, HD,
                                                      fin, fin, ah, s1, s2, hs, hid, nx1, 1, 0);
        else
            k_mfma<0,2><<<nx1 * 16, 256, 0, stream>>>(xhi, nullptr, whh[l], whl[l], hh, HD,
                                                      fin, fin, ah, s1, s2, hs, hid, nx1, 1, 0);

        // per-head masked softmax aggregation (4 waves/block, one (node,head) each)
        k_aggb<<<NN * NH / 4, 256, 0, stream>>>(hh, s1, s2, rp, ci, ghi, hid, HD, c8sh);

        // --- ho = hcat @ Wo  (split-K bf16 partial stores), z<->XCD colocate ---
        int nx2 = fout / 64;
        k_mfma<1,2><<<nx2 * 16 * SKO, 256, 0, stream>>>(ghi, nullptr, woh[l], wol[l], hopart,
                                                        fout, HD, HD / SKO,
                                                        nullptr, nullptr, nullptr, -1, fout,
                                                        nx2, SKO, 1);

        // reduce bf16 partials -> ho (bf16) + t1/t2 (fp32 dots)
        k_red<<<NN / 4, 256, 0, stream>>>(hopart, ho, ao, t1, t2, fout, SKO);

        float* outF = (l == 5) ? (float*)d_out : nullptr;
        k_aggs<<<NN / 4, 256, 0, stream>>>(ho, t1, t2, rp, ci, outF, xhi, fout);
    }
}